// Round 11
// baseline (143.359 us; speedup 1.0000x reference)
//
#include <hip/hip_runtime.h>
#include <math.h>

#define HWSZ 65536
#define EPSF 1e-5f
#define PSTR 4680   // shorts per patch region: 65 rows * 72 (row 64 = zeros)

typedef __attribute__((ext_vector_type(8))) short bf8v;
typedef __attribute__((ext_vector_type(4))) float f4v;
typedef __attribute__((ext_vector_type(4))) unsigned int u4v;
typedef __attribute__((ext_vector_type(2))) unsigned int u2v;
typedef unsigned int uint32;

// bf16 ws offsets (shorts)
#define W_HID_OFF   0
#define W_X1_OFF    4096
#define W_PROJ_OFF  8192
#define W_OUT_OFF   10240
#define W_DWB0_OFF  14336
#define W_DWB2_OFF  15360
// f32 ws region starts at float index 8192
#define F_DWT   0
#define F_CI1T  576
#define F_CI2T  1088
#define F_IW1T  1344
#define F_SI1T  1600

__device__ __forceinline__ float bl(uint32 u){ return __uint_as_float(u<<16); }
__device__ __forceinline__ float bh(uint32 u){ return __uint_as_float(u & 0xffff0000u); }
__device__ __forceinline__ uint32 pk2(float a, float b){
  uint32 r; asm("v_cvt_pk_bf16_f32 %0, %1, %2" : "=v"(r) : "v"(a), "v"(b)); return r;
}
__device__ __forceinline__ unsigned short bfr(float x){
  uint32 u = __float_as_uint(x); u += 0x7fffu + ((u>>16)&1u); return (unsigned short)(u>>16);
}
__device__ __forceinline__ float rcp_f(float x){ float r; asm("v_rcp_f32 %0, %1" : "=v"(r) : "v"(x)); return r; }
__device__ __forceinline__ float exp2_f(float x){ float r; asm("v_exp_f32 %0, %1" : "=v"(r) : "v"(x)); return r; }
__device__ __forceinline__ float sigm(float v){
  return rcp_f(1.0f + exp2_f(v * -1.4426950408889634f));
}

// erf via Abramowitz-Stegun 7.1.26 (|err| < 1.5e-7), branchless
__device__ __attribute__((noinline)) f4v gelu4(f4v v){
  f4v r;
  #pragma unroll
  for (int i=0;i<4;++i){
    float x  = v[i];
    float z  = fabsf(x) * 0.7071067811865476f;
    float t  = rcp_f(fmaf(0.3275911f, z, 1.0f));
    float p  = t*fmaf(t, fmaf(t, fmaf(t, fmaf(t, 1.061405429f, -1.453152027f),
                       1.421413741f), -0.284496736f), 0.254829592f);
    float ex = exp2_f(-(z*z)*1.4426950408889634f);
    float er = fmaf(-p, ex, 1.0f);
    float s  = copysignf(er, x);
    float hx = 0.5f*x;
    r[i] = fmaf(hx, s, hx);
  }
  return r;
}

__global__ void prep_w(const float* __restrict__ a0, const float* __restrict__ a1,
                       const float* __restrict__ a2, const float* __restrict__ a3,
                       const float* __restrict__ a4, const float* __restrict__ a5,
                       unsigned short* __restrict__ ws){
  int i = blockIdx.x*256 + threadIdx.x;
  if (i >= 16384) return;
  float v;
  if      (i < 4096)  v = a0[i];
  else if (i < 8192)  v = a1[i-4096];
  else if (i < 10240) v = a2[i-8192];
  else if (i < 14336) v = a3[i-10240];
  else if (i < 15360) v = a4[i-14336];
  else                v = a5[i-15360];
  ws[i] = bfr(v);
}

__global__ void prep_t(const float* __restrict__ dw, const float* __restrict__ ci1,
                       const float* __restrict__ ci2, const float* __restrict__ iw1,
                       const float* __restrict__ sw1, float* __restrict__ wf){
  int i = blockIdx.x*256 + threadIdx.x;
  if (i >= 1728) return;
  float v;
  if (i < 576)        { int k=i/64, c=i%64;            v = dw[c*9+k]; }
  else if (i < 1088)  { int j=i-576,  c=j/8, m=j%8;    v = ci1[m*64+c]; }
  else if (i < 1344)  { int j=i-1088, m=j/32, o=j%32;  v = ci2[o*8+m]; }
  else if (i < 1600)  { int j=i-1344, c=j/8, m=j%8;    v = iw1[m*32+c]; }
  else                { int j=i-1600, c=j/4, m=j%4;    v = sw1[m*32+c]; }
  wf[i] = v;
}

// Block = 256 thr = 2 patches x 2 waves. Discipline: every in-place LDS tile
// update is {reads+MFMA} -> __syncthreads -> {writes} -> __syncthreads, since
// the partner wave reads the same region.
__global__ __launch_bounds__(256, 5)
void gmlp_fused(const float* __restrict__ x,
                const float* __restrict__ b_hid,
                const float* __restrict__ xcnn_b1,
                const float* __restrict__ xcnn_ln_w, const float* __restrict__ xcnn_ln_b,
                const float* __restrict__ xcnn_dw_b,
                const float* __restrict__ ci_b1,
                const float* __restrict__ ci_ln_w, const float* __restrict__ ci_ln_b,
                const float* __restrict__ ci_b2,
                const float* __restrict__ si_b1,
                const float* __restrict__ si_ln_w, const float* __restrict__ si_ln_b,
                const float* __restrict__ si_w2,   const float* __restrict__ si_b2,
                const float* __restrict__ proj_b,
                const float* __restrict__ out_b,
                const float* __restrict__ sgu_ln_w, const float* __restrict__ sgu_ln_b,
                const float* __restrict__ idw_b1,
                const float* __restrict__ idw_bn_w, const float* __restrict__ idw_bn_b,
                const float* __restrict__ idw_w2,  const float* __restrict__ idw_b2,
                const unsigned short* __restrict__ wsw,
                float* __restrict__ out)
{
    __shared__ __align__(16) unsigned short bufS[2*PSTR];
    __shared__ __align__(16) float segate_s[2][32];

    const float* wf = (const float*)wsw + 8192;

    const int tx  = threadIdx.x;
    const int wp_ = tx >> 7;          // patch within block (0/1)
    const int wv  = (tx >> 6) & 1;    // wave within patch (0/1)
    const int t   = tx & 63;          // pixel
    const int l4  = t & 15, g4 = t >> 4;
    const int py  = t >> 3,  px = t & 7;

    const int bid = blockIdx.x;       // grid = B * 32 * 16
    const int s16 = bid & 15;
    const int ph  = (bid >> 4) & 31;
    const int bb  = bid >> 9;

    unsigned short* Wp = bufS + wp_*PSTR;

    // cooperative I/O mapping: block covers 16 cols x 8 rows x 64 ch
    const int ch2 = tx >> 7;          // channel-quad selector
    const int r128 = tx & 127;
    const int ty  = r128 >> 4;        // 0..7
    const int txx = r128 & 15;        // 0..15
    const int lp  = txx >> 3;
    const int lpx = txx & 7;
    const int yx  = ty*256 + txx;
    const float* xbase = x + (bb*64)*HWSZ + (ph*8)*256 + s16*16;
    unsigned short* ldst = bufS + lp*PSTR + (ty*8 + lpx)*72 + ch2*4;

    // ---------------- P1: cooperative load + zero-row ----------------
    #pragma unroll 1
    for (int c8 = 0; c8 < 8; ++c8) {
        int c = c8*8 + ch2*4;
        u2v w;
        w[0] = pk2(__builtin_nontemporal_load(xbase + c*HWSZ + yx),
                   __builtin_nontemporal_load(xbase + (c+1)*HWSZ + yx));
        w[1] = pk2(__builtin_nontemporal_load(xbase + (c+2)*HWSZ + yx),
                   __builtin_nontemporal_load(xbase + (c+3)*HWSZ + yx));
        *(u2v*)(ldst + c8*8) = w;
    }
    if (tx < 18) *(u4v*)(bufS + (tx/9)*PSTR + 64*72 + (tx%9)*8) = (u4v){0,0,0,0};
    __syncthreads();

    // ---------------- P2: hidden GEMM (n-half per wave) + bias + gelu ----------------
    f4v acc[4][2];
    #pragma unroll
    for (int m = 0; m < 4; ++m) { acc[m][0] = (f4v){0,0,0,0}; acc[m][1] = (f4v){0,0,0,0}; }
    {
        bf8v a0[4], a1[4], w0[2], w1[2];
        #pragma unroll
        for (int nn = 0; nn < 2; ++nn) {
            w0[nn] = *(const bf8v*)(wsw + W_HID_OFF + ((wv*2+nn)*16+l4)*64 + g4*8);
            w1[nn] = *(const bf8v*)(wsw + W_HID_OFF + ((wv*2+nn)*16+l4)*64 + 32 + g4*8);
        }
        #pragma unroll
        for (int m = 0; m < 4; ++m) a0[m] = *(const bf8v*)(Wp + (m*16+l4)*72 + g4*8);
        #pragma unroll
        for (int m = 0; m < 4; ++m) a1[m] = *(const bf8v*)(Wp + (m*16+l4)*72 + 32 + g4*8);
        #pragma unroll
        for (int m = 0; m < 4; ++m)
            #pragma unroll
            for (int nn = 0; nn < 2; ++nn) {
                acc[m][nn] = __builtin_amdgcn_mfma_f32_16x16x32_bf16(a0[m], w0[nn], acc[m][nn], 0,0,0);
                acc[m][nn] = __builtin_amdgcn_mfma_f32_16x16x32_bf16(a1[m], w1[nn], acc[m][nn], 0,0,0);
            }
    }
    {
        float bh0 = b_hid[(wv*2)*16 + l4], bh1 = b_hid[(wv*2+1)*16 + l4];
        #pragma unroll
        for (int m = 0; m < 4; ++m) {
            f4v q0, q1;
            #pragma unroll
            for (int r = 0; r < 4; ++r) { q0[r] = acc[m][0][r] + bh0; q1[r] = acc[m][1][r] + bh1; }
            acc[m][0] = gelu4(q0); acc[m][1] = gelu4(q1);
        }
    }
    __syncthreads();
    #pragma unroll
    for (int m = 0; m < 4; ++m)
        #pragma unroll
        for (int nn = 0; nn < 2; ++nn)
            #pragma unroll
            for (int r = 0; r < 4; ++r)
                Wp[(m*16 + g4*4 + r)*72 + (wv*2+nn)*16 + l4] = bfr(acc[m][nn][r]);
    __syncthreads();

    // hid readback: wave0 keeps res (ch 0..31), wave1 keeps gate (ch 32..63)
    uint32 hpk[16];
    #pragma unroll
    for (int q4 = 0; q4 < 4; ++q4) {
        u4v v = *(const u4v*)(Wp + t*72 + wv*32 + q4*8);
        #pragma unroll
        for (int j = 0; j < 4; ++j) hpk[q4*4 + j] = v[j];
    }

    // ---------------- P3: xcnn GEMM + bias ----------------
    #pragma unroll
    for (int m = 0; m < 4; ++m) { acc[m][0] = (f4v){0,0,0,0}; acc[m][1] = (f4v){0,0,0,0}; }
    {
        bf8v a0[4], a1[4], w0[2], w1[2];
        #pragma unroll
        for (int nn = 0; nn < 2; ++nn) {
            w0[nn] = *(const bf8v*)(wsw + W_X1_OFF + ((wv*2+nn)*16+l4)*64 + g4*8);
            w1[nn] = *(const bf8v*)(wsw + W_X1_OFF + ((wv*2+nn)*16+l4)*64 + 32 + g4*8);
        }
        #pragma unroll
        for (int m = 0; m < 4; ++m) a0[m] = *(const bf8v*)(Wp + (m*16+l4)*72 + g4*8);
        #pragma unroll
        for (int m = 0; m < 4; ++m) a1[m] = *(const bf8v*)(Wp + (m*16+l4)*72 + 32 + g4*8);
        #pragma unroll
        for (int m = 0; m < 4; ++m)
            #pragma unroll
            for (int nn = 0; nn < 2; ++nn) {
                acc[m][nn] = __builtin_amdgcn_mfma_f32_16x16x32_bf16(a0[m], w0[nn], acc[m][nn], 0,0,0);
                acc[m][nn] = __builtin_amdgcn_mfma_f32_16x16x32_bf16(a1[m], w1[nn], acc[m][nn], 0,0,0);
            }
    }
    {
        float bx0 = xcnn_b1[(wv*2)*16 + l4], bx1 = xcnn_b1[(wv*2+1)*16 + l4];
        #pragma unroll
        for (int m = 0; m < 4; ++m)
            #pragma unroll
            for (int r = 0; r < 4; ++r) { acc[m][0][r] += bx0; acc[m][1][r] += bx1; }
    }
    __syncthreads();
    #pragma unroll
    for (int m = 0; m < 4; ++m)
        #pragma unroll
        for (int nn = 0; nn < 2; ++nn)
            #pragma unroll
            for (int r = 0; r < 4; ++r)
                Wp[(m*16 + g4*4 + r)*72 + (wv*2+nn)*16 + l4] = bfr(acc[m][nn][r]);
    __syncthreads();

    // ---------------- LN over 64 ch: stats both waves, write own half ----------------
    {
        float s = 0.f;
        #pragma unroll 1
        for (int q8 = 0; q8 < 8; ++q8) {
            u4v v = *(const u4v*)(Wp + t*72 + q8*8);
            #pragma unroll
            for (int j = 0; j < 4; ++j) s += bl(v[j]) + bh(v[j]);
        }
        float mu = s * (1.f/64.f);
        float s2 = 0.f;
        #pragma unroll 1
        for (int q8 = 0; q8 < 8; ++q8) {
            u4v v = *(const u4v*)(Wp + t*72 + q8*8);
            #pragma unroll
            for (int j = 0; j < 4; ++j) {
                float d0 = bl(v[j]) - mu, d1 = bh(v[j]) - mu;
                s2 = fmaf(d0, d0, fmaf(d1, d1, s2));
            }
        }
        float rstd = rsqrtf(s2*(1.f/64.f) + EPSF);
        __syncthreads();     // all stats reads done before any normalize-writes
        #pragma unroll 1
        for (int q8 = wv*4; q8 < wv*4 + 4; ++q8) {
            u4v v = *(const u4v*)(Wp + t*72 + q8*8);
            u4v w;
            #pragma unroll
            for (int j = 0; j < 4; ++j) {
                int c = q8*8 + 2*j;
                float a = (bl(v[j]) - mu)*rstd*xcnn_ln_w[c]   + xcnn_ln_b[c];
                float b = (bh(v[j]) - mu)*rstd*xcnn_ln_w[c+1] + xcnn_ln_b[c+1];
                w[j] = pk2(a, b);
            }
            *(u4v*)(Wp + t*72 + q8*8) = w;
        }
    }
    __syncthreads();

    // ---------------- P4: depthwise 3x3 + gelu (wave wv = channel half wv) ----------------
    {
        float xh[32];
        #pragma unroll
        for (int o = 0; o < 32; ++o) xh[o] = xcnn_dw_b[wv*32 + o];
        #pragma unroll 1
        for (int ki = 0; ki < 3; ++ki) {
            #pragma unroll 1
            for (int kj = 0; kj < 3; ++kj) {
                int rr = py + ki - 1, cc = px + kj - 1;
                bool val = ((unsigned)rr < 8u) && ((unsigned)cc < 8u);
                int pnn = val ? rr*8 + cc : 64;
                const unsigned short* rp = Wp + pnn*72 + wv*32;
                const float* wpt = wf + F_DWT + (ki*3+kj)*64 + wv*32;
                #pragma unroll
                for (int c8 = 0; c8 < 4; ++c8) {
                    u4v v = *(const u4v*)(rp + c8*8);
                    #pragma unroll
                    for (int j = 0; j < 4; ++j) {
                        int c = c8*8 + 2*j;
                        xh[c]   = fmaf(bl(v[j]), wpt[c],   xh[c]);
                        xh[c+1] = fmaf(bh(v[j]), wpt[c+1], xh[c+1]);
                    }
                }
            }
        }
        #pragma unroll
        for (int g = 0; g < 8; ++g) {
            f4v q = (f4v){xh[4*g], xh[4*g+1], xh[4*g+2], xh[4*g+3]};
            q = gelu4(q);
            xh[4*g]=q[0]; xh[4*g+1]=q[1]; xh[4*g+2]=q[2]; xh[4*g+3]=q[3];
        }
        #pragma unroll
        for (int c8 = 0; c8 < 4; ++c8) {
            u4v w;
            #pragma unroll
            for (int j = 0; j < 4; ++j) w[j] = pk2(xh[c8*8+2*j], xh[c8*8+2*j+1]);
            *(u4v*)(Wp + t*72 + wv*32 + c8*8) = w;
        }
    }
    __syncthreads();

    // ---------------- P4.5: pooled (wave1) + proj GEMM (n-block wv) ----------------
    float pc = 0.f;
    if (wv == 1) {
        float ps = 0.f;
        #pragma unroll 1
        for (int p8 = 0; p8 < 8; ++p8) {
            #pragma unroll
            for (int q = 0; q < 8; ++q) ps += bl((uint32)Wp[(p8*8+q)*72 + t]);
        }
        pc = ps * (1.f/64.f);
    }
    f4v accp[4];
    #pragma unroll
    for (int m = 0; m < 4; ++m) accp[m] = (f4v){0,0,0,0};
    {
        bf8v a0[4], a1[4], w0, w1;
        w0 = *(const bf8v*)(wsw + W_PROJ_OFF + (wv*16+l4)*64 + g4*8);
        w1 = *(const bf8v*)(wsw + W_PROJ_OFF + (wv*16+l4)*64 + 32 + g4*8);
        #pragma unroll
        for (int m = 0; m < 4; ++m) a0[m] = *(const bf8v*)(Wp + (m*16+l4)*72 + g4*8);
        #pragma unroll
        for (int m = 0; m < 4; ++m) a1[m] = *(const bf8v*)(Wp + (m*16+l4)*72 + 32 + g4*8);
        #pragma unroll
        for (int m = 0; m < 4; ++m) {
            accp[m] = __builtin_amdgcn_mfma_f32_16x16x32_bf16(a0[m], w0, accp[m], 0,0,0);
            accp[m] = __builtin_amdgcn_mfma_f32_16x16x32_bf16(a1[m], w1, accp[m], 0,0,0);
        }
    }
    {
        float bp = proj_b[wv*16 + l4];
        #pragma unroll
        for (int m = 0; m < 4; ++m)
            #pragma unroll
            for (int r = 0; r < 4; ++r) accp[m][r] += bp;
    }
    __syncthreads();
    #pragma unroll
    for (int m = 0; m < 4; ++m)
        #pragma unroll
        for (int r = 0; r < 4; ++r)
            Wp[(m*16 + g4*4 + r)*72 + wv*16 + l4] = bfr(accp[m][r]);
    __syncthreads();
    // xp readback: own half only (cols wv*16 .. +15) -- written by this wave
    uint32 xppk8[8];
    #pragma unroll
    for (int q4 = 0; q4 < 2; ++q4) {
        u4v v = *(const u4v*)(Wp + t*72 + wv*16 + q4*8);
        #pragma unroll
        for (int j = 0; j < 4; ++j) xppk8[q4*4 + j] = v[j];
    }
    __syncthreads();   // xp reads done before wave1 overwrites cols 0..31 with sg

    // ---------------- P5: SE gate + SGU-LN (wave 1 only; it holds gate) ----------------
    if (wv == 1) {
        float pt[8];
        {
            f4v wa = *(const f4v*)(wf + F_CI1T + t*8);
            f4v wb = *(const f4v*)(wf + F_CI1T + t*8 + 4);
            #pragma unroll
            for (int m = 0; m < 4; ++m) { pt[m] = wa[m]*pc; pt[4+m] = wb[m]*pc; }
        }
        #pragma unroll
        for (int st = 1; st < 64; st <<= 1)
            #pragma unroll
            for (int m = 0; m < 8; ++m) pt[m] += __shfl_xor(pt[m], st, 64);
        float t8[8];
        #pragma unroll
        for (int m = 0; m < 8; ++m) t8[m] = pt[m] + ci_b1[m];
        float s = 0.f;
        #pragma unroll
        for (int m = 0; m < 8; ++m) s += t8[m];
        float mu = s * 0.125f;
        float q2 = 0.f;
        #pragma unroll
        for (int m = 0; m < 8; ++m) { float d = t8[m]-mu; q2 = fmaf(d,d,q2); }
        float rstd = rsqrtf(q2*0.125f + EPSF);
        #pragma unroll
        for (int m = 0; m < 8; ++m) t8[m] = (t8[m]-mu)*rstd*ci_ln_w[m] + ci_ln_b[m];
        f4v qa = gelu4((f4v){t8[0],t8[1],t8[2],t8[3]});
        f4v qb = gelu4((f4v){t8[4],t8[5],t8[6],t8[7]});
        t8[0]=qa[0]; t8[1]=qa[1]; t8[2]=qa[2]; t8[3]=qa[3];
        t8[4]=qb[0]; t8[5]=qb[1]; t8[6]=qb[2]; t8[7]=qb[3];
        if (t < 32) {
            float a = ci_b2[t];
            #pragma unroll
            for (int m = 0; m < 8; ++m) a = fmaf(wf[F_CI2T + m*32 + t], t8[m], a);
            segate_s[wp_][t] = sigm(a);
        }
        // same-wave write->read through LDS: ordered, no barrier needed
        float sg[32];
        #pragma unroll
        for (int g = 0; g < 8; ++g) {
            f4v e = *(const f4v*)&segate_s[wp_][g*4];
            #pragma unroll
            for (int r = 0; r < 4; ++r) {
                int o = g*4 + r;
                uint32 pkv = hpk[o/2];           // gate half
                float gv = (o & 1) ? bh(pkv) : bl(pkv);
                sg[o] = gv * e[r];
            }
        }
        float ss = 0.f;
        #pragma unroll
        for (int o = 0; o < 32; ++o) ss += sg[o];
        float mu2 = ss * (1.f/32.f);
        float qq = 0.f;
        #pragma unroll
        for (int o = 0; o < 32; ++o) { float d = sg[o]-mu2; qq = fmaf(d,d,qq); }
        float rstd2 = rsqrtf(qq*(1.f/32.f) + EPSF);
        #pragma unroll
        for (int o = 0; o < 32; ++o) sg[o] = (sg[o]-mu2)*rstd2*sgu_ln_w[o] + sgu_ln_b[o];
        #pragma unroll
        for (int c8 = 0; c8 < 4; ++c8) {
            u4v w;
            #pragma unroll
            for (int j = 0; j < 4; ++j) w[j] = pk2(sg[c8*8+2*j], sg[c8*8+2*j+1]);
            *(u4v*)(Wp + t*72 + c8*8) = w;
        }
    }
    __syncthreads();

    // ---------------- P7: dwb_w0 GEMM -> Gt (cols 32..63; disjoint from reads) ----------------
    {
        f4v accg[4];
        #pragma unroll
        for (int m = 0; m < 4; ++m) accg[m] = (f4v){0,0,0,0};
        bf8v av[4];
        bf8v w0 = *(const bf8v*)(wsw + W_DWB0_OFF + (wv*16+l4)*32 + g4*8);
        #pragma unroll
        for (int m = 0; m < 4; ++m) av[m] = *(const bf8v*)(Wp + (m*16+l4)*72 + g4*8);
        #pragma unroll
        for (int m = 0; m < 4; ++m)
            accg[m] = __builtin_amdgcn_mfma_f32_16x16x32_bf16(av[m], w0, accg[m], 0,0,0);
        #pragma unroll
        for (int m = 0; m < 4; ++m)
            #pragma unroll
            for (int r = 0; r < 4; ++r) {
                int q = m*16 + g4*4 + r;
                Wp[((q>>5)*32 + wv*16 + l4)*72 + 32 + (q & 31)] = bfr(accg[m][r]);
            }
    }
    __syncthreads();

    // ---------------- P8: idw kernel gen + dyn 7x7 via MFMA (alternating M builds) ----------------
    float t8b[8];
    #pragma unroll
    for (int m = 0; m < 8; ++m) t8b[m] = idw_b1[m];
    #pragma unroll 1
    for (int c = 0; c < 32; ++c) {
        float gv = bl((uint32)Wp[((t>>5)*32 + c)*72 + 32 + (t & 31)]);
        #pragma unroll
        for (int m = 0; m < 8; ++m) t8b[m] = fmaf(wf[F_IW1T + c*8 + m], gv, t8b[m]);
    }
    #pragma unroll
    for (int m = 0; m < 8; ++m)
        t8b[m] = fmaxf(t8b[m]*(idw_bn_w[m]*0.9999950000374997f) + idw_bn_b[m], 0.f);

    f4v accd[4];
    #pragma unroll
    for (int m = 0; m < 4; ++m) accd[m] = (f4v){0,0,0,0};
    #pragma unroll 1
    for (int s = 0; s < 2; ++s) {
        if (wv == s) {   // builder wave for K-block s
            #pragma unroll
            for (int i = 0; i < 4; ++i) *(u4v*)(Wp + t*72 + i*8) = (u4v){0,0,0,0};
            #pragma unroll 1
            for (int ki = 0; ki < 7; ++ki) {
                int rr = py + ki - 3;
                #pragma unroll 1
                for (int kj = 0; kj < 7; ++kj) {
                    int cc = px + kj - 3;
                    int k  = ki*7 + kj;
                    float wk = idw_b2[k];
                    #pragma unroll
                    for (int m = 0; m < 8; ++m) wk = fmaf(idw_w2[k*8 + m], t8b[m], wk);
                    int q = rr*8 + cc;
                    if (((unsigned)rr < 8u) && ((unsigned)cc < 8u) && ((q >> 5) == s))
                        Wp[t*72 + (q & 31)] = bfr(wk);
                }
            }
        }
        __syncthreads();
        bf8v aM[4];
        bf8v bG = *(const bf8v*)(Wp + (s*32 + wv*16 + l4)*72 + 32 + g4*8);
        #pragma unroll
        for (int m = 0; m < 4; ++m) aM[m] = *(const bf8v*)(Wp + (m*16+l4)*72 + g4*8);
        #pragma unroll
        for (int m = 0; m < 4; ++m)
            accd[m] = __builtin_amdgcn_mfma_f32_16x16x32_bf16(aM[m], bG, accd[m], 0,0,0);
        __syncthreads();   // all aM reads done before next build / C-write
    }
    #pragma unroll
    for (int m = 0; m < 4; ++m)
        #pragma unroll
        for (int r = 0; r < 4; ++r)
            Wp[(m*16 + g4*4 + r)*72 + wv*16 + l4] = bfr(accd[m][r]);
    __syncthreads();

    // ---------------- P9: dwb_w2 GEMM -> g2; sgu = g2 * res (wave 0) ----------------
    {
        f4v accg[4];
        #pragma unroll
        for (int m = 0; m < 4; ++m) accg[m] = (f4v){0,0,0,0};
        bf8v av[4];
        bf8v w0 = *(const bf8v*)(wsw + W_DWB2_OFF + (wv*16+l4)*32 + g4*8);
        #pragma unroll
        for (int m = 0; m < 4; ++m) av[m] = *(const bf8v*)(Wp + (m*16+l4)*72 + g4*8);
        #pragma unroll
        for (int m = 0; m < 4; ++m)
            accg[m] = __builtin_amdgcn_mfma_f32_16x16x32_bf16(av[m], w0, accg[m], 0,0,0);
        __syncthreads();
        #pragma unroll
        for (int m = 0; m < 4; ++m)
            #pragma unroll
            for (int r = 0; r < 4; ++r)
                Wp[(m*16 + g4*4 + r)*72 + wv*16 + l4] = bfr(accg[m][r]);
    }
    __syncthreads();
    if (wv == 0) {   // wave 0 holds res
        #pragma unroll
        for (int q8 = 0; q8 < 4; ++q8) {
            u4v v = *(const u4v*)(Wp + t*72 + q8*8);
            u4v w;
            #pragma unroll
            for (int j = 0; j < 4; ++j) {
                int q = q8*4 + j;
                w[j] = pk2(bl(v[j]) * bl(hpk[q]), bh(v[j]) * bh(hpk[q]));
            }
            *(u4v*)(Wp + t*72 + 32 + q8*8) = w;
        }
    }
    __syncthreads();

    // ---------------- P10: si gate (redundant both waves), stage xp*siv ----------------
    float siv;
    {
        float s1[4];
        #pragma unroll
        for (int m = 0; m < 4; ++m) s1[m] = si_b1[m];
        #pragma unroll 1
        for (int c8 = 0; c8 < 4; ++c8) {
            u4v v = *(const u4v*)(Wp + t*72 + 32 + c8*8);
            #pragma unroll
            for (int j = 0; j < 4; ++j) {
                int c = c8*8 + 2*j;
                float a0 = bl(v[j]), a1 = bh(v[j]);
                #pragma unroll
                for (int m = 0; m < 4; ++m) {
                    s1[m] = fmaf(wf[F_SI1T + c*4 + m],     a0, s1[m]);
                    s1[m] = fmaf(wf[F_SI1T + (c+1)*4 + m], a1, s1[m]);
                }
            }
        }
        float s = s1[0]+s1[1]+s1[2]+s1[3];
        float mu = s * 0.25f;
        float q2 = 0.f;
        #pragma unroll
        for (int m = 0; m < 4; ++m) { float d = s1[m]-mu; q2 = fmaf(d,d,q2); }
        float rstd = rsqrtf(q2*0.25f + EPSF);
        f4v q;
        #pragma unroll
        for (int m = 0; m < 4; ++m) q[m] = (s1[m]-mu)*rstd*si_ln_w[m] + si_ln_b[m];
        q = gelu4(q);
        float a = si_b2[0];
        #pragma unroll
        for (int m = 0; m < 4; ++m) a = fmaf(si_w2[m], q[m], a);
        siv = sigm(a);
    }
    #pragma unroll
    for (int c4 = 0; c4 < 2; ++c4) {
        u4v w;
        #pragma unroll
        for (int j = 0; j < 4; ++j) {
            int q = c4*4 + j;
            w[j] = pk2(bl(xppk8[q])*siv, bh(xppk8[q])*siv);
        }
        *(u4v*)(Wp + t*72 + wv*16 + c4*8) = w;
    }
    __syncthreads();

    // ---------------- P11: out GEMM + bias ----------------
    #pragma unroll
    for (int m = 0; m < 4; ++m) { acc[m][0] = (f4v){0,0,0,0}; acc[m][1] = (f4v){0,0,0,0}; }
    {
        bf8v a0[4], a1[4], w0[2], w1[2];
        #pragma unroll
        for (int nn = 0; nn < 2; ++nn) {
            w0[nn] = *(const bf8v*)(wsw + W_OUT_OFF + ((wv*2+nn)*16+l4)*64 + g4*8);
            w1[nn] = *(const bf8v*)(wsw + W_OUT_OFF + ((wv*2+nn)*16+l4)*64 + 32 + g4*8);
        }
        #pragma unroll
        for (int m = 0; m < 4; ++m) a0[m] = *(const bf8v*)(Wp + (m*16+l4)*72 + g4*8);
        #pragma unroll
        for (int m = 0; m < 4; ++m) a1[m] = *(const bf8v*)(Wp + (m*16+l4)*72 + 32 + g4*8);
        #pragma unroll
        for (int m = 0; m < 4; ++m)
            #pragma unroll
            for (int nn = 0; nn < 2; ++nn) {
                acc[m][nn] = __builtin_amdgcn_mfma_f32_16x16x32_bf16(a0[m], w0[nn], acc[m][nn], 0,0,0);
                acc[m][nn] = __builtin_amdgcn_mfma_f32_16x16x32_bf16(a1[m], w1[nn], acc[m][nn], 0,0,0);
            }
    }
    {
        float bo0 = out_b[(wv*2)*16 + l4], bo1 = out_b[(wv*2+1)*16 + l4];
        #pragma unroll
        for (int m = 0; m < 4; ++m)
            #pragma unroll
            for (int r = 0; r < 4; ++r) { acc[m][0][r] += bo0; acc[m][1][r] += bo1; }
    }
    __syncthreads();
    #pragma unroll
    for (int m = 0; m < 4; ++m)
        #pragma unroll
        for (int nn = 0; nn < 2; ++nn)
            #pragma unroll
            for (int r = 0; r < 4; ++r)
                Wp[(m*16 + g4*4 + r)*72 + (wv*2+nn)*16 + l4] = bfr(acc[m][nn][r]);
    __syncthreads();

    // ---------------- P12: cooperative store ----------------
    {
        float* obase = out + (bb*64)*HWSZ + (ph*8)*256 + s16*16;
        const unsigned short* lsrc = bufS + lp*PSTR + (ty*8 + lpx)*72 + ch2*4;
        #pragma unroll 1
        for (int c8 = 0; c8 < 8; ++c8) {
            int c = c8*8 + ch2*4;
            u2v v = *(const u2v*)(lsrc + c8*8);
            __builtin_nontemporal_store(bl(v[0]), obase + c*HWSZ + yx);
            __builtin_nontemporal_store(bh(v[0]), obase + (c+1)*HWSZ + yx);
            __builtin_nontemporal_store(bl(v[1]), obase + (c+2)*HWSZ + yx);
            __builtin_nontemporal_store(bh(v[1]), obase + (c+3)*HWSZ + yx);
        }
    }
}

extern "C" void kernel_launch(void* const* d_in, const int* in_sizes, int n_in,
                              void* d_out, int out_size, void* d_ws, size_t ws_size,
                              hipStream_t stream) {
    const float* p[35];
    for (int i = 0; i < 35; ++i) p[i] = (const float*)d_in[i];
    unsigned short* ws = (unsigned short*)d_ws;
    float* wsf = (float*)ws + 8192;

    prep_w<<<64, 256, 0, stream>>>(p[1], p[3], p[21], p[23], p[27], p[34], ws);
    prep_t<<<7, 256, 0, stream>>>(p[7], p[9], p[13], p[28], p[15], wsf);

    const int B = in_sizes[0] / (64 * 256 * 256);   // = 4
    dim3 grid(B * 32 * 16), block(256);
    gmlp_fused<<<grid, block, 0, stream>>>(
        p[0],  p[2],  p[4],  p[5],  p[6],  p[8],
        p[10], p[11], p[12], p[14],
        p[16], p[17], p[18], p[19], p[20],
        p[22], p[24], p[25], p[26],
        p[29], p[30], p[31], p[32], p[33],
        ws, (float*)d_out);
}

// Round 12
// 112.467 us; speedup vs baseline: 1.2747x; 1.2747x over previous
//
#include <hip/hip_runtime.h>
#include <math.h>

#define HWSZ 65536
#define EPSF 1e-5f
#define PSTR 4680   // shorts per patch region: 65 rows * 72 (row 64 = zeros)

typedef __attribute__((ext_vector_type(8))) short bf8v;
typedef __attribute__((ext_vector_type(4))) float f4v;
typedef __attribute__((ext_vector_type(4))) unsigned int u4v;
typedef unsigned int uint32;

// bf16 ws offsets (shorts)
#define W_HID_OFF   0
#define W_X1_OFF    4096
#define W_PROJ_OFF  8192
#define W_OUT_OFF   10240
#define W_DWB0_OFF  14336
#define W_DWB2_OFF  15360
// f32 ws region starts at float index 8192
#define F_DWT   0
#define F_CI1T  576
#define F_CI2T  1088
#define F_IW1T  1344
#define F_SI1T  1600

__device__ __forceinline__ float bl(uint32 u){ return __uint_as_float(u<<16); }
__device__ __forceinline__ float bh(uint32 u){ return __uint_as_float(u & 0xffff0000u); }
__device__ __forceinline__ uint32 pk2(float a, float b){
  uint32 r; asm("v_cvt_pk_bf16_f32 %0, %1, %2" : "=v"(r) : "v"(a), "v"(b)); return r;
}
__device__ __forceinline__ unsigned short bfr(float x){
  uint32 u = __float_as_uint(x); u += 0x7fffu + ((u>>16)&1u); return (unsigned short)(u>>16);
}
__device__ __forceinline__ float rcp_f(float x){ float r; asm("v_rcp_f32 %0, %1" : "=v"(r) : "v"(x)); return r; }
__device__ __forceinline__ float exp2_f(float x){ float r; asm("v_exp_f32 %0, %1" : "=v"(r) : "v"(x)); return r; }
__device__ __forceinline__ float sigm(float v){
  return rcp_f(1.0f + exp2_f(v * -1.4426950408889634f));
}

// erf via Abramowitz-Stegun 7.1.26 (|err| < 1.5e-7), branchless
__device__ __attribute__((noinline)) f4v gelu4(f4v v){
  f4v r;
  #pragma unroll
  for (int i=0;i<4;++i){
    float x  = v[i];
    float z  = fabsf(x) * 0.7071067811865476f;
    float t  = rcp_f(fmaf(0.3275911f, z, 1.0f));
    float p  = t*fmaf(t, fmaf(t, fmaf(t, fmaf(t, 1.061405429f, -1.453152027f),
                       1.421413741f), -0.284496736f), 0.254829592f);
    float ex = exp2_f(-(z*z)*1.4426950408889634f);
    float er = fmaf(-p, ex, 1.0f);
    float s  = copysignf(er, x);
    float hx = 0.5f*x;
    r[i] = fmaf(hx, s, hx);
  }
  return r;
}

__global__ void prep_w(const float* __restrict__ a0, const float* __restrict__ a1,
                       const float* __restrict__ a2, const float* __restrict__ a3,
                       const float* __restrict__ a4, const float* __restrict__ a5,
                       unsigned short* __restrict__ ws){
  int i = blockIdx.x*256 + threadIdx.x;
  if (i >= 16384) return;
  float v;
  if      (i < 4096)  v = a0[i];
  else if (i < 8192)  v = a1[i-4096];
  else if (i < 10240) v = a2[i-8192];
  else if (i < 14336) v = a3[i-10240];
  else if (i < 15360) v = a4[i-14336];
  else                v = a5[i-15360];
  ws[i] = bfr(v);
}

__global__ void prep_t(const float* __restrict__ dw, const float* __restrict__ ci1,
                       const float* __restrict__ ci2, const float* __restrict__ iw1,
                       const float* __restrict__ sw1, float* __restrict__ wf){
  int i = blockIdx.x*256 + threadIdx.x;
  if (i >= 1728) return;
  float v;
  if (i < 576)        { int k=i/64, c=i%64;            v = dw[c*9+k]; }
  else if (i < 1088)  { int j=i-576,  c=j/8, m=j%8;    v = ci1[m*64+c]; }
  else if (i < 1344)  { int j=i-1088, m=j/32, o=j%32;  v = ci2[o*8+m]; }
  else if (i < 1600)  { int j=i-1344, c=j/8, m=j%8;    v = iw1[m*32+c]; }
  else                { int j=i-1600, c=j/4, m=j%4;    v = sw1[m*32+c]; }
  wf[i] = v;
}

// Block = 256 thr = 4 waves; each wave owns TWO patches (in-wave ILP). No
// interior barriers: each patch is touched by exactly one wave between the
// load/store barriers, and a wave's LDS ops execute in program order.
__global__ __launch_bounds__(256, 2)
void gmlp_fused(const float* __restrict__ x,
                const float* __restrict__ b_hid,
                const float* __restrict__ xcnn_b1,
                const float* __restrict__ xcnn_ln_w, const float* __restrict__ xcnn_ln_b,
                const float* __restrict__ xcnn_dw_b,
                const float* __restrict__ ci_b1,
                const float* __restrict__ ci_ln_w, const float* __restrict__ ci_ln_b,
                const float* __restrict__ ci_b2,
                const float* __restrict__ si_b1,
                const float* __restrict__ si_ln_w, const float* __restrict__ si_ln_b,
                const float* __restrict__ si_w2,   const float* __restrict__ si_b2,
                const float* __restrict__ proj_b,
                const float* __restrict__ out_b,
                const float* __restrict__ sgu_ln_w, const float* __restrict__ sgu_ln_b,
                const float* __restrict__ idw_b1,
                const float* __restrict__ idw_bn_w, const float* __restrict__ idw_bn_b,
                const float* __restrict__ idw_w2,  const float* __restrict__ idw_b2,
                const unsigned short* __restrict__ wsw,
                float* __restrict__ out)
{
    __shared__ __align__(16) unsigned short bufS[8*PSTR];
    __shared__ __align__(16) float segate_s[8][32];

    const float* wf = (const float*)wsw + 8192;

    const int tx  = threadIdx.x;
    const int wid = tx >> 6;
    const int t   = tx & 63;
    const int l4  = t & 15, g4 = t >> 4;
    const int py  = t >> 3,  px = t & 7;

    const int bid = blockIdx.x;       // grid = B * 32 * 4
    const int s64 = bid & 3;
    const int ph  = (bid >> 2) & 31;
    const int bb  = bid >> 7;

    // I/O mapping: block covers 64 cols x 8 rows x 64 ch (8 patches)
    const int ty  = tx >> 5;          // 0..7
    const int txx = tx & 31;
    const float* xbase = x + (bb*64)*HWSZ + (ph*8)*256 + s64*64;

    // ---------------- P1: cooperative coalesced load (256B rows) ----------------
    #pragma unroll 1
    for (int h = 0; h < 2; ++h) {
        unsigned short* ldst = bufS + (h*4 + (txx>>3))*PSTR + (ty*8 + (txx&7))*72;
        const float* xb = xbase + ty*256 + h*32 + txx;
        #pragma unroll 2
        for (int c8 = 0; c8 < 8; ++c8) {
            u4v w;
            #pragma unroll
            for (int j = 0; j < 4; ++j) {
                int c = c8*8 + 2*j;
                w[j] = pk2(__builtin_nontemporal_load(xb + c*HWSZ),
                           __builtin_nontemporal_load(xb + (c+1)*HWSZ));
            }
            *(u4v*)(ldst + c8*8) = w;
        }
    }
    if (tx < 72) *(u4v*)(bufS + (tx/9)*PSTR + 64*72 + (tx%9)*8) = (u4v){0,0,0,0};
    __syncthreads();

    uint32 hpk[2][32];   // per patch: res [0..15], gate [16..31]
    uint32 xppk[2][16];
    float  pcv[2];

    // ---------------- P2: hidden GEMM + bias + gelu (unrolled p) ----------------
    #pragma unroll
    for (int p = 0; p < 2; ++p) {
        unsigned short* Wp = bufS + (wid*2+p)*PSTR;
        f4v acc[4][4];
        #pragma unroll
        for (int m = 0; m < 4; ++m)
            #pragma unroll
            for (int n = 0; n < 4; ++n) acc[m][n] = (f4v){0,0,0,0};
        {
            bf8v a0[4], a1[4];
            #pragma unroll
            for (int m = 0; m < 4; ++m) a0[m] = *(const bf8v*)(Wp + (m*16+l4)*72 + g4*8);
            #pragma unroll
            for (int m = 0; m < 4; ++m) a1[m] = *(const bf8v*)(Wp + (m*16+l4)*72 + 32 + g4*8);
            #pragma unroll
            for (int n = 0; n < 4; ++n) {
                bf8v w0 = *(const bf8v*)(wsw + W_HID_OFF + (n*16+l4)*64 + g4*8);
                bf8v w1 = *(const bf8v*)(wsw + W_HID_OFF + (n*16+l4)*64 + 32 + g4*8);
                #pragma unroll
                for (int m = 0; m < 4; ++m) {
                    acc[m][n] = __builtin_amdgcn_mfma_f32_16x16x32_bf16(a0[m], w0, acc[m][n], 0,0,0);
                    acc[m][n] = __builtin_amdgcn_mfma_f32_16x16x32_bf16(a1[m], w1, acc[m][n], 0,0,0);
                }
            }
        }
        #pragma unroll
        for (int n = 0; n < 4; ++n) {
            float bhid = b_hid[n*16 + l4];
            #pragma unroll
            for (int m = 0; m < 4; ++m) {
                f4v q;
                #pragma unroll
                for (int r = 0; r < 4; ++r) q[r] = acc[m][n][r] + bhid;
                acc[m][n] = gelu4(q);
            }
        }
        #pragma unroll
        for (int m = 0; m < 4; ++m)
            #pragma unroll
            for (int n = 0; n < 4; ++n)
                #pragma unroll
                for (int r = 0; r < 4; ++r)
                    Wp[(m*16 + g4*4 + r)*72 + n*16 + l4] = bfr(acc[m][n][r]);
        #pragma unroll
        for (int q8 = 0; q8 < 8; ++q8) {
            u4v v = *(const u4v*)(Wp + t*72 + q8*8);
            #pragma unroll
            for (int j = 0; j < 4; ++j) hpk[p][q8*4 + j] = v[j];
        }
    }

    // ---------------- P3: xcnn GEMM + bias + per-pixel LN (unrolled p) ----------------
    #pragma unroll
    for (int p = 0; p < 2; ++p) {
        unsigned short* Wp = bufS + (wid*2+p)*PSTR;
        f4v acc[4][4];
        #pragma unroll
        for (int m = 0; m < 4; ++m)
            #pragma unroll
            for (int n = 0; n < 4; ++n) acc[m][n] = (f4v){0,0,0,0};
        {
            bf8v a0[4], a1[4];
            #pragma unroll
            for (int m = 0; m < 4; ++m) a0[m] = *(const bf8v*)(Wp + (m*16+l4)*72 + g4*8);
            #pragma unroll
            for (int m = 0; m < 4; ++m) a1[m] = *(const bf8v*)(Wp + (m*16+l4)*72 + 32 + g4*8);
            #pragma unroll
            for (int n = 0; n < 4; ++n) {
                bf8v w0 = *(const bf8v*)(wsw + W_X1_OFF + (n*16+l4)*64 + g4*8);
                bf8v w1 = *(const bf8v*)(wsw + W_X1_OFF + (n*16+l4)*64 + 32 + g4*8);
                #pragma unroll
                for (int m = 0; m < 4; ++m) {
                    acc[m][n] = __builtin_amdgcn_mfma_f32_16x16x32_bf16(a0[m], w0, acc[m][n], 0,0,0);
                    acc[m][n] = __builtin_amdgcn_mfma_f32_16x16x32_bf16(a1[m], w1, acc[m][n], 0,0,0);
                }
            }
        }
        #pragma unroll
        for (int n = 0; n < 4; ++n) {
            float bx = xcnn_b1[n*16 + l4];
            #pragma unroll
            for (int m = 0; m < 4; ++m)
                #pragma unroll
                for (int r = 0; r < 4; ++r) acc[m][n][r] += bx;
        }
        #pragma unroll
        for (int m = 0; m < 4; ++m)
            #pragma unroll
            for (int n = 0; n < 4; ++n)
                #pragma unroll
                for (int r = 0; r < 4; ++r)
                    Wp[(m*16 + g4*4 + r)*72 + n*16 + l4] = bfr(acc[m][n][r]);
        // LN over 64 ch (3 rolled passes over own row)
        float s = 0.f;
        #pragma unroll 1
        for (int q8 = 0; q8 < 8; ++q8) {
            u4v v = *(const u4v*)(Wp + t*72 + q8*8);
            #pragma unroll
            for (int j = 0; j < 4; ++j) s += bl(v[j]) + bh(v[j]);
        }
        float mu = s * (1.f/64.f);
        float s2 = 0.f;
        #pragma unroll 1
        for (int q8 = 0; q8 < 8; ++q8) {
            u4v v = *(const u4v*)(Wp + t*72 + q8*8);
            #pragma unroll
            for (int j = 0; j < 4; ++j) {
                float d0 = bl(v[j]) - mu, d1 = bh(v[j]) - mu;
                s2 = fmaf(d0, d0, fmaf(d1, d1, s2));
            }
        }
        float rstd = rsqrtf(s2*(1.f/64.f) + EPSF);
        #pragma unroll 1
        for (int q8 = 0; q8 < 8; ++q8) {
            u4v v = *(const u4v*)(Wp + t*72 + q8*8);
            u4v w;
            #pragma unroll
            for (int j = 0; j < 4; ++j) {
                int c = q8*8 + 2*j;
                float a = (bl(v[j]) - mu)*rstd*xcnn_ln_w[c]   + xcnn_ln_b[c];
                float b = (bh(v[j]) - mu)*rstd*xcnn_ln_w[c+1] + xcnn_ln_b[c+1];
                w[j] = pk2(a, b);
            }
            *(u4v*)(Wp + t*72 + q8*8) = w;
        }
    }

    // ---------------- P4: depthwise 3x3 + gelu (rolled p; zero-row border) ----------------
    #pragma unroll 1
    for (int p = 0; p < 2; ++p) {
        unsigned short* Wp = bufS + (wid*2+p)*PSTR;
        #pragma unroll 1
        for (int h = 0; h < 2; ++h) {
            float xh[32];
            #pragma unroll
            for (int o = 0; o < 32; ++o) xh[o] = xcnn_dw_b[h*32 + o];
            #pragma unroll 1
            for (int ki = 0; ki < 3; ++ki) {
                #pragma unroll 1
                for (int kj = 0; kj < 3; ++kj) {
                    int rr = py + ki - 1, cc = px + kj - 1;
                    bool val = ((unsigned)rr < 8u) && ((unsigned)cc < 8u);
                    int pnn = val ? rr*8 + cc : 64;
                    const unsigned short* rp = Wp + pnn*72 + h*32;
                    const float* wpt = wf + F_DWT + (ki*3+kj)*64 + h*32;
                    #pragma unroll
                    for (int c8 = 0; c8 < 4; ++c8) {
                        u4v v = *(const u4v*)(rp + c8*8);
                        #pragma unroll
                        for (int j = 0; j < 4; ++j) {
                            int c = c8*8 + 2*j;
                            xh[c]   = fmaf(bl(v[j]), wpt[c],   xh[c]);
                            xh[c+1] = fmaf(bh(v[j]), wpt[c+1], xh[c+1]);
                        }
                    }
                }
            }
            #pragma unroll
            for (int g = 0; g < 8; ++g) {
                f4v q = (f4v){xh[4*g], xh[4*g+1], xh[4*g+2], xh[4*g+3]};
                q = gelu4(q);
                xh[4*g]=q[0]; xh[4*g+1]=q[1]; xh[4*g+2]=q[2]; xh[4*g+3]=q[3];
            }
            #pragma unroll
            for (int c8 = 0; c8 < 4; ++c8) {
                u4v w;
                #pragma unroll
                for (int j = 0; j < 4; ++j) w[j] = pk2(xh[c8*8+2*j], xh[c8*8+2*j+1]);
                *(u4v*)(Wp + t*72 + h*32 + c8*8) = w;
            }
        }
    }

    // ---------------- P4.5: channel mean + proj GEMM (unrolled p) ----------------
    #pragma unroll
    for (int p = 0; p < 2; ++p) {
        unsigned short* Wp = bufS + (wid*2+p)*PSTR;
        {
            float ps = 0.f;
            #pragma unroll 1
            for (int p8 = 0; p8 < 8; ++p8) {
                #pragma unroll
                for (int q = 0; q < 8; ++q) ps += bl((uint32)Wp[(p8*8+q)*72 + t]);
            }
            pcv[p] = ps * (1.f/64.f);
        }
        f4v accp[4][2];
        #pragma unroll
        for (int m = 0; m < 4; ++m) { accp[m][0] = (f4v){0,0,0,0}; accp[m][1] = (f4v){0,0,0,0}; }
        {
            bf8v a0[4], a1[4];
            #pragma unroll
            for (int m = 0; m < 4; ++m) a0[m] = *(const bf8v*)(Wp + (m*16+l4)*72 + g4*8);
            #pragma unroll
            for (int m = 0; m < 4; ++m) a1[m] = *(const bf8v*)(Wp + (m*16+l4)*72 + 32 + g4*8);
            #pragma unroll
            for (int n = 0; n < 2; ++n) {
                bf8v w0 = *(const bf8v*)(wsw + W_PROJ_OFF + (n*16+l4)*64 + g4*8);
                bf8v w1 = *(const bf8v*)(wsw + W_PROJ_OFF + (n*16+l4)*64 + 32 + g4*8);
                #pragma unroll
                for (int m = 0; m < 4; ++m) {
                    accp[m][n] = __builtin_amdgcn_mfma_f32_16x16x32_bf16(a0[m], w0, accp[m][n], 0,0,0);
                    accp[m][n] = __builtin_amdgcn_mfma_f32_16x16x32_bf16(a1[m], w1, accp[m][n], 0,0,0);
                }
            }
        }
        {
            float bp0 = proj_b[l4], bp1 = proj_b[16 + l4];
            #pragma unroll
            for (int m = 0; m < 4; ++m)
                #pragma unroll
                for (int r = 0; r < 4; ++r) { accp[m][0][r] += bp0; accp[m][1][r] += bp1; }
        }
        #pragma unroll
        for (int m = 0; m < 4; ++m)
            #pragma unroll
            for (int n = 0; n < 2; ++n)
                #pragma unroll
                for (int r = 0; r < 4; ++r)
                    Wp[(m*16 + g4*4 + r)*72 + n*16 + l4] = bfr(accp[m][n][r]);
        #pragma unroll
        for (int q8 = 0; q8 < 4; ++q8) {
            u4v v = *(const u4v*)(Wp + t*72 + q8*8);
            #pragma unroll
            for (int j = 0; j < 4; ++j) xppk[p][q8*4 + j] = v[j];
        }
    }

    // ---------------- P5: SE gate + SGU-LN + stage sg (unrolled p) ----------------
    #pragma unroll
    for (int p = 0; p < 2; ++p) {
        unsigned short* Wp = bufS + (wid*2+p)*PSTR;
        float pt[8];
        {
            f4v wa = *(const f4v*)(wf + F_CI1T + t*8);
            f4v wb = *(const f4v*)(wf + F_CI1T + t*8 + 4);
            #pragma unroll
            for (int m = 0; m < 4; ++m) { pt[m] = wa[m]*pcv[p]; pt[4+m] = wb[m]*pcv[p]; }
        }
        #pragma unroll
        for (int st = 1; st < 64; st <<= 1)
            #pragma unroll
            for (int m = 0; m < 8; ++m) pt[m] += __shfl_xor(pt[m], st, 64);
        float t8[8];
        #pragma unroll
        for (int m = 0; m < 8; ++m) t8[m] = pt[m] + ci_b1[m];
        float s = 0.f;
        #pragma unroll
        for (int m = 0; m < 8; ++m) s += t8[m];
        float mu = s * 0.125f;
        float q2 = 0.f;
        #pragma unroll
        for (int m = 0; m < 8; ++m) { float d = t8[m]-mu; q2 = fmaf(d,d,q2); }
        float rstd = rsqrtf(q2*0.125f + EPSF);
        #pragma unroll
        for (int m = 0; m < 8; ++m) t8[m] = (t8[m]-mu)*rstd*ci_ln_w[m] + ci_ln_b[m];
        f4v qa = gelu4((f4v){t8[0],t8[1],t8[2],t8[3]});
        f4v qb = gelu4((f4v){t8[4],t8[5],t8[6],t8[7]});
        t8[0]=qa[0]; t8[1]=qa[1]; t8[2]=qa[2]; t8[3]=qa[3];
        t8[4]=qb[0]; t8[5]=qb[1]; t8[6]=qb[2]; t8[7]=qb[3];
        if (t < 32) {
            float a = ci_b2[t];
            #pragma unroll
            for (int m = 0; m < 8; ++m) a = fmaf(wf[F_CI2T + m*32 + t], t8[m], a);
            segate_s[wid*2+p][t] = sigm(a);
        }
        // same-wave LDS write->read: in-order
        float sg[32];
        #pragma unroll
        for (int g = 0; g < 8; ++g) {
            f4v e = *(const f4v*)&segate_s[wid*2+p][g*4];
            #pragma unroll
            for (int r = 0; r < 4; ++r) {
                int o = g*4 + r;
                uint32 pkv = hpk[p][16 + o/2];
                float gv = (o & 1) ? bh(pkv) : bl(pkv);
                sg[o] = gv * e[r];
            }
        }
        float ss = 0.f;
        #pragma unroll
        for (int o = 0; o < 32; ++o) ss += sg[o];
        float mu2 = ss * (1.f/32.f);
        float qq = 0.f;
        #pragma unroll
        for (int o = 0; o < 32; ++o) { float d = sg[o]-mu2; qq = fmaf(d,d,qq); }
        float rstd2 = rsqrtf(qq*(1.f/32.f) + EPSF);
        #pragma unroll
        for (int o = 0; o < 32; ++o) sg[o] = (sg[o]-mu2)*rstd2*sgu_ln_w[o] + sgu_ln_b[o];
        #pragma unroll
        for (int c8 = 0; c8 < 4; ++c8) {
            u4v w;
            #pragma unroll
            for (int j = 0; j < 4; ++j) w[j] = pk2(sg[c8*8+2*j], sg[c8*8+2*j+1]);
            *(u4v*)(Wp + t*72 + c8*8) = w;
        }
    }

    // ---------------- P7: dwb_w0 GEMM -> Gt transposed (cols 32..63) (unrolled p) ----------------
    #pragma unroll
    for (int p = 0; p < 2; ++p) {
        unsigned short* Wp = bufS + (wid*2+p)*PSTR;
        f4v accg[4][2];
        #pragma unroll
        for (int m = 0; m < 4; ++m) { accg[m][0] = (f4v){0,0,0,0}; accg[m][1] = (f4v){0,0,0,0}; }
        bf8v av[4];
        #pragma unroll
        for (int m = 0; m < 4; ++m) av[m] = *(const bf8v*)(Wp + (m*16+l4)*72 + g4*8);
        #pragma unroll
        for (int n = 0; n < 2; ++n) {
            bf8v w0 = *(const bf8v*)(wsw + W_DWB0_OFF + (n*16+l4)*32 + g4*8);
            #pragma unroll
            for (int m = 0; m < 4; ++m)
                accg[m][n] = __builtin_amdgcn_mfma_f32_16x16x32_bf16(av[m], w0, accg[m][n], 0,0,0);
        }
        #pragma unroll
        for (int m = 0; m < 4; ++m)
            #pragma unroll
            for (int n = 0; n < 2; ++n)
                #pragma unroll
                for (int r = 0; r < 4; ++r) {
                    int q = m*16 + g4*4 + r;
                    Wp[((q>>5)*32 + n*16 + l4)*72 + 32 + (q & 31)] = bfr(accg[m][n][r]);
                }
    }

    // ---------------- P8: idw kernel gen + dyn 7x7 via MFMA (rolled p) ----------------
    #pragma unroll 1
    for (int p = 0; p < 2; ++p) {
        unsigned short* Wp = bufS + (wid*2+p)*PSTR;
        float t8b[8];
        #pragma unroll
        for (int m = 0; m < 8; ++m) t8b[m] = idw_b1[m];
        #pragma unroll 1
        for (int c = 0; c < 32; ++c) {
            float gv = bl((uint32)Wp[((t>>5)*32 + c)*72 + 32 + (t & 31)]);
            #pragma unroll
            for (int m = 0; m < 8; ++m) t8b[m] = fmaf(wf[F_IW1T + c*8 + m], gv, t8b[m]);
        }
        #pragma unroll
        for (int m = 0; m < 8; ++m)
            t8b[m] = fmaxf(t8b[m]*(idw_bn_w[m]*0.9999950000374997f) + idw_bn_b[m], 0.f);

        f4v accd[4][2];
        #pragma unroll
        for (int m = 0; m < 4; ++m) { accd[m][0] = (f4v){0,0,0,0}; accd[m][1] = (f4v){0,0,0,0}; }
        #pragma unroll 1
        for (int s = 0; s < 2; ++s) {
            #pragma unroll
            for (int i = 0; i < 4; ++i) *(u4v*)(Wp + t*72 + i*8) = (u4v){0,0,0,0};
            #pragma unroll 1
            for (int ki = 0; ki < 7; ++ki) {
                int rr = py + ki - 3;
                #pragma unroll 1
                for (int kj = 0; kj < 7; ++kj) {
                    int cc = px + kj - 3;
                    int k  = ki*7 + kj;
                    float wk = idw_b2[k];
                    #pragma unroll
                    for (int m = 0; m < 8; ++m) wk = fmaf(idw_w2[k*8 + m], t8b[m], wk);
                    int q = rr*8 + cc;
                    if (((unsigned)rr < 8u) && ((unsigned)cc < 8u) && ((q >> 5) == s))
                        Wp[t*72 + (q & 31)] = bfr(wk);
                }
            }
            bf8v aM[4], bG[2];
            #pragma unroll
            for (int m = 0; m < 4; ++m) aM[m] = *(const bf8v*)(Wp + (m*16+l4)*72 + g4*8);
            #pragma unroll
            for (int n = 0; n < 2; ++n) bG[n] = *(const bf8v*)(Wp + (s*32 + n*16 + l4)*72 + 32 + g4*8);
            #pragma unroll
            for (int m = 0; m < 4; ++m)
                #pragma unroll
                for (int n = 0; n < 2; ++n)
                    accd[m][n] = __builtin_amdgcn_mfma_f32_16x16x32_bf16(aM[m], bG[n], accd[m][n], 0,0,0);
        }
        #pragma unroll
        for (int m = 0; m < 4; ++m)
            #pragma unroll
            for (int n = 0; n < 2; ++n)
                #pragma unroll
                for (int r = 0; r < 4; ++r)
                    Wp[(m*16 + g4*4 + r)*72 + n*16 + l4] = bfr(accd[m][n][r]);
    }

    // ---------------- P9: dwb_w2 GEMM -> g2; sgu = g2*res -> cols 32..63 (unrolled p) ----------------
    #pragma unroll
    for (int p = 0; p < 2; ++p) {
        unsigned short* Wp = bufS + (wid*2+p)*PSTR;
        f4v accg[4][2];
        #pragma unroll
        for (int m = 0; m < 4; ++m) { accg[m][0] = (f4v){0,0,0,0}; accg[m][1] = (f4v){0,0,0,0}; }
        bf8v av[4];
        #pragma unroll
        for (int m = 0; m < 4; ++m) av[m] = *(const bf8v*)(Wp + (m*16+l4)*72 + g4*8);
        #pragma unroll
        for (int n = 0; n < 2; ++n) {
            bf8v w0 = *(const bf8v*)(wsw + W_DWB2_OFF + (n*16+l4)*32 + g4*8);
            #pragma unroll
            for (int m = 0; m < 4; ++m)
                accg[m][n] = __builtin_amdgcn_mfma_f32_16x16x32_bf16(av[m], w0, accg[m][n], 0,0,0);
        }
        #pragma unroll
        for (int m = 0; m < 4; ++m)
            #pragma unroll
            for (int n = 0; n < 2; ++n)
                #pragma unroll
                for (int r = 0; r < 4; ++r)
                    Wp[(m*16 + g4*4 + r)*72 + n*16 + l4] = bfr(accg[m][n][r]);
        // sgu = g2 * res  (read own row cols 0..31, write packed to cols 32..63)
        #pragma unroll
        for (int q8 = 0; q8 < 4; ++q8) {
            u4v v = *(const u4v*)(Wp + t*72 + q8*8);
            u4v w;
            #pragma unroll
            for (int j = 0; j < 4; ++j) {
                int q = q8*4 + j;
                w[j] = pk2(bl(v[j]) * bl(hpk[p][q]), bh(v[j]) * bh(hpk[p][q]));
            }
            *(u4v*)(Wp + t*72 + 32 + q8*8) = w;
        }
    }

    // ---------------- P10: si gate + stage xp*siv (unrolled p) ----------------
    #pragma unroll
    for (int p = 0; p < 2; ++p) {
        unsigned short* Wp = bufS + (wid*2+p)*PSTR;
        float siv;
        {
            float s1[4];
            #pragma unroll
            for (int m = 0; m < 4; ++m) s1[m] = si_b1[m];
            #pragma unroll 1
            for (int c8 = 0; c8 < 4; ++c8) {
                u4v v = *(const u4v*)(Wp + t*72 + 32 + c8*8);
                #pragma unroll
                for (int j = 0; j < 4; ++j) {
                    int c = c8*8 + 2*j;
                    float a0 = bl(v[j]), a1 = bh(v[j]);
                    #pragma unroll
                    for (int m = 0; m < 4; ++m) {
                        s1[m] = fmaf(wf[F_SI1T + c*4 + m],     a0, s1[m]);
                        s1[m] = fmaf(wf[F_SI1T + (c+1)*4 + m], a1, s1[m]);
                    }
                }
            }
            float s = s1[0]+s1[1]+s1[2]+s1[3];
            float mu = s * 0.25f;
            float q2 = 0.f;
            #pragma unroll
            for (int m = 0; m < 4; ++m) { float d = s1[m]-mu; q2 = fmaf(d,d,q2); }
            float rstd = rsqrtf(q2*0.25f + EPSF);
            f4v q;
            #pragma unroll
            for (int m = 0; m < 4; ++m) q[m] = (s1[m]-mu)*rstd*si_ln_w[m] + si_ln_b[m];
            q = gelu4(q);
            float a = si_b2[0];
            #pragma unroll
            for (int m = 0; m < 4; ++m) a = fmaf(si_w2[m], q[m], a);
            siv = sigm(a);
        }
        #pragma unroll
        for (int c8 = 0; c8 < 4; ++c8) {
            u4v w;
            #pragma unroll
            for (int j = 0; j < 4; ++j) {
                int q = c8*4 + j;
                w[j] = pk2(bl(xppk[p][q])*siv, bh(xppk[p][q])*siv);
            }
            *(u4v*)(Wp + t*72 + c8*8) = w;
        }
    }

    // ---------------- P11: out GEMM + bias (unrolled p) ----------------
    #pragma unroll
    for (int p = 0; p < 2; ++p) {
        unsigned short* Wp = bufS + (wid*2+p)*PSTR;
        f4v acc[4][4];
        #pragma unroll
        for (int m = 0; m < 4; ++m)
            #pragma unroll
            for (int n = 0; n < 4; ++n) acc[m][n] = (f4v){0,0,0,0};
        {
            bf8v a0[4], a1[4];
            #pragma unroll
            for (int m = 0; m < 4; ++m) a0[m] = *(const bf8v*)(Wp + (m*16+l4)*72 + g4*8);
            #pragma unroll
            for (int m = 0; m < 4; ++m) a1[m] = *(const bf8v*)(Wp + (m*16+l4)*72 + 32 + g4*8);
            #pragma unroll
            for (int n = 0; n < 4; ++n) {
                bf8v w0 = *(const bf8v*)(wsw + W_OUT_OFF + (n*16+l4)*64 + g4*8);
                bf8v w1 = *(const bf8v*)(wsw + W_OUT_OFF + (n*16+l4)*64 + 32 + g4*8);
                #pragma unroll
                for (int m = 0; m < 4; ++m) {
                    acc[m][n] = __builtin_amdgcn_mfma_f32_16x16x32_bf16(a0[m], w0, acc[m][n], 0,0,0);
                    acc[m][n] = __builtin_amdgcn_mfma_f32_16x16x32_bf16(a1[m], w1, acc[m][n], 0,0,0);
                }
            }
        }
        #pragma unroll
        for (int n = 0; n < 4; ++n) {
            float bo = out_b[n*16 + l4];
            #pragma unroll
            for (int m = 0; m < 4; ++m)
                #pragma unroll
                for (int r = 0; r < 4; ++r) acc[m][n][r] += bo;
        }
        #pragma unroll
        for (int m = 0; m < 4; ++m)
            #pragma unroll
            for (int n = 0; n < 4; ++n)
                #pragma unroll
                for (int r = 0; r < 4; ++r)
                    Wp[(m*16 + g4*4 + r)*72 + n*16 + l4] = bfr(acc[m][n][r]);
    }
    __syncthreads();

    // ---------------- P12: cooperative coalesced store ----------------
    {
        float* obase = out + (bb*64)*HWSZ + (ph*8)*256 + s64*64;
        #pragma unroll 1
        for (int h = 0; h < 2; ++h) {
            const unsigned short* lsrc = bufS + (h*4 + (txx>>3))*PSTR + (ty*8 + (txx&7))*72;
            float* ob = obase + ty*256 + h*32 + txx;
            #pragma unroll 1
            for (int c8 = 0; c8 < 8; ++c8) {
                u4v v = *(const u4v*)(lsrc + c8*8);
                #pragma unroll
                for (int j = 0; j < 4; ++j) {
                    int c = c8*8 + 2*j;
                    __builtin_nontemporal_store(bl(v[j]), ob + c*HWSZ);
                    __builtin_nontemporal_store(bh(v[j]), ob + (c+1)*HWSZ);
                }
            }
        }
    }
}

extern "C" void kernel_launch(void* const* d_in, const int* in_sizes, int n_in,
                              void* d_out, int out_size, void* d_ws, size_t ws_size,
                              hipStream_t stream) {
    const float* p[35];
    for (int i = 0; i < 35; ++i) p[i] = (const float*)d_in[i];
    unsigned short* ws = (unsigned short*)d_ws;
    float* wsf = (float*)ws + 8192;

    prep_w<<<64, 256, 0, stream>>>(p[1], p[3], p[21], p[23], p[27], p[34], ws);
    prep_t<<<7, 256, 0, stream>>>(p[7], p[9], p[13], p[28], p[15], wsf);

    const int B = in_sizes[0] / (64 * 256 * 256);   // = 4
    dim3 grid(B * 32 * 4), block(256);
    gmlp_fused<<<grid, block, 0, stream>>>(
        p[0],  p[2],  p[4],  p[5],  p[6],  p[8],
        p[10], p[11], p[12], p[14],
        p[16], p[17], p[18], p[19], p[20],
        p[22], p[24], p[25], p[26],
        p[29], p[30], p[31], p[32], p[33],
        ws, (float*)d_out);
}

// Round 13
// 84.792 us; speedup vs baseline: 1.6907x; 1.3264x over previous
//
#include <hip/hip_runtime.h>
#include <math.h>

#define HWSZ 65536
#define EPSF 1e-5f
#define PSTR 4680   // shorts per patch LDS region: 65 rows * 72 (row 64 = zeros)

typedef __attribute__((ext_vector_type(8))) short bf8v;
typedef __attribute__((ext_vector_type(4))) float f4v;
typedef __attribute__((ext_vector_type(4))) unsigned int u4v;
typedef unsigned int uint32;

// bf16 ws offsets (shorts)
#define W_HID_OFF   0
#define W_X1_OFF    4096
#define W_PROJ_OFF  8192
#define W_OUT_OFF   10240
#define W_DWB0_OFF  14336
#define W_DWB2_OFF  15360
// f32 ws region starts at float index 8192
#define F_DWT   0
#define F_CI1T  576
#define F_CI2T  1088
#define F_IW1T  1344
#define F_SI1T  1600

__device__ __forceinline__ float bl(uint32 u){ return __uint_as_float(u<<16); }
__device__ __forceinline__ float bh(uint32 u){ return __uint_as_float(u & 0xffff0000u); }
__device__ __forceinline__ uint32 pk2(float a, float b){
  uint32 r; asm("v_cvt_pk_bf16_f32 %0, %1, %2" : "=v"(r) : "v"(a), "v"(b)); return r;
}
__device__ __forceinline__ unsigned short bfr(float x){
  uint32 u = __float_as_uint(x); u += 0x7fffu + ((u>>16)&1u); return (unsigned short)(u>>16);
}
__device__ __forceinline__ float rcp_f(float x){ float r; asm("v_rcp_f32 %0, %1" : "=v"(r) : "v"(x)); return r; }
__device__ __forceinline__ float exp2_f(float x){ float r; asm("v_exp_f32 %0, %1" : "=v"(r) : "v"(x)); return r; }
__device__ __forceinline__ float sigm(float v){
  return rcp_f(1.0f + exp2_f(v * -1.4426950408889634f));
}

// fast gelu: x * sigmoid(1.702 x)  (max |err| ~0.02, well under the 0.99
// absmax budget; 5 VALU/elem vs ~14 for the erf form, and small enough to
// inline at all ~35 sites, removing call overhead + regalloc constraints)
__device__ __forceinline__ f4v gelu4(f4v v){
  f4v r;
  #pragma unroll
  for (int i=0;i<4;++i){
    float x = v[i];
    r[i] = x * rcp_f(1.0f + exp2_f(x * -2.4554669596f));  // 1.702*log2(e)
  }
  return r;
}

// wave-local LDS fence: waits lgkmcnt only (in-flight VMEM loads cross it)
#define WSYNC() asm volatile("s_waitcnt lgkmcnt(0)" ::: "memory")

__global__ void prep_w(const float* __restrict__ a0, const float* __restrict__ a1,
                       const float* __restrict__ a2, const float* __restrict__ a3,
                       const float* __restrict__ a4, const float* __restrict__ a5,
                       unsigned short* __restrict__ ws){
  int i = blockIdx.x*256 + threadIdx.x;
  if (i >= 16384) return;
  float v;
  if      (i < 4096)  v = a0[i];
  else if (i < 8192)  v = a1[i-4096];
  else if (i < 10240) v = a2[i-8192];
  else if (i < 14336) v = a3[i-10240];
  else if (i < 15360) v = a4[i-14336];
  else                v = a5[i-15360];
  ws[i] = bfr(v);
}

__global__ void prep_t(const float* __restrict__ dw, const float* __restrict__ ci1,
                       const float* __restrict__ ci2, const float* __restrict__ iw1,
                       const float* __restrict__ sw1, float* __restrict__ wf){
  int i = blockIdx.x*256 + threadIdx.x;
  if (i >= 1728) return;
  float v;
  if (i < 576)        { int k=i/64, c=i%64;            v = dw[c*9+k]; }
  else if (i < 1088)  { int j=i-576,  c=j/8, m=j%8;    v = ci1[m*64+c]; }
  else if (i < 1344)  { int j=i-1088, m=j/32, o=j%32;  v = ci2[o*8+m]; }
  else if (i < 1600)  { int j=i-1344, c=j/8, m=j%8;    v = iw1[m*32+c]; }
  else                { int j=i-1600, c=j/4, m=j%4;    v = sw1[m*32+c]; }
  wf[i] = v;
}

__global__ __launch_bounds__(256, 4)
void gmlp_fused(const float* __restrict__ x,
                const float* __restrict__ b_hid,
                const float* __restrict__ xcnn_b1,
                const float* __restrict__ xcnn_ln_w, const float* __restrict__ xcnn_ln_b,
                const float* __restrict__ xcnn_dw_b,
                const float* __restrict__ ci_b1,
                const float* __restrict__ ci_ln_w, const float* __restrict__ ci_ln_b,
                const float* __restrict__ ci_b2,
                const float* __restrict__ si_b1,
                const float* __restrict__ si_ln_w, const float* __restrict__ si_ln_b,
                const float* __restrict__ si_w2,   const float* __restrict__ si_b2,
                const float* __restrict__ proj_b,
                const float* __restrict__ out_b,
                const float* __restrict__ sgu_ln_w, const float* __restrict__ sgu_ln_b,
                const float* __restrict__ idw_b1,
                const float* __restrict__ idw_bn_w, const float* __restrict__ idw_bn_b,
                const float* __restrict__ idw_w2,  const float* __restrict__ idw_b2,
                const unsigned short* __restrict__ wsw,
                float* __restrict__ out)
{
    __shared__ __align__(16) unsigned short bufS[4*PSTR];
    __shared__ __align__(16) float segate_s[4][32];

    const float* wf = (const float*)wsw + 8192;

    const int tx  = threadIdx.x;
    const int wid = tx >> 6;
    const int t   = tx & 63;
    const int l4  = t & 15, g4 = t >> 4;
    const int py  = t >> 3,  px = t & 7;

    const int bid   = blockIdx.x;     // grid = B * 32 * 8
    const int strip = bid & 7;
    const int ph    = (bid >> 3) & 31;
    const int bb    = bid >> 8;

    unsigned short* Wp = bufS + wid*PSTR;

    const int ty  = tx >> 5;
    const int txx = tx & 31;
    const int lp  = txx >> 3;
    const int lpx = txx & 7;
    const int yx  = ty*256 + txx;
    const float* xbase = x + (bb*64)*HWSZ + (ph*8)*256 + strip*32;
    unsigned short* ldst = bufS + lp*PSTR + (ty*8 + lpx)*72;

    // ---------------- P1: cooperative coalesced load + zero-row + hidW prefetch ----------------
    #pragma unroll 1
    for (int c8 = 0; c8 < 8; ++c8) {
        u4v w;
        #pragma unroll
        for (int j = 0; j < 4; ++j) {
            int c = c8*8 + 2*j;
            float a = __builtin_nontemporal_load(xbase + c*HWSZ + yx);
            float b = __builtin_nontemporal_load(xbase + (c+1)*HWSZ + yx);
            w[j] = pk2(a, b);
        }
        *(u4v*)(ldst + c8*8) = w;
    }
    if (t < 9) *(u4v*)(Wp + 64*72 + t*8) = (u4v){0,0,0,0};   // row 64 = zeros
    // prefetch hidden weights (consumed in P2; cover = barrier + ds_reads)
    bf8v hidW[8];
    #pragma unroll
    for (int s = 0; s < 2; ++s)
        #pragma unroll
        for (int n = 0; n < 4; ++n)
            hidW[s*4+n] = *(const bf8v*)(wsw + W_HID_OFF + (n*16+l4)*64 + s*32 + g4*8);
    __syncthreads();

    // ---------------- P2: hidden GEMM + bias + gelu ----------------
    f4v acc[4][4];
    #pragma unroll
    for (int m = 0; m < 4; ++m)
        #pragma unroll
        for (int n = 0; n < 4; ++n)
            acc[m][n] = (f4v){0.f,0.f,0.f,0.f};
    {
        bf8v a0[4], a1[4];
        #pragma unroll
        for (int m = 0; m < 4; ++m) a0[m] = *(const bf8v*)(Wp + (m*16 + l4)*72 + g4*8);
        #pragma unroll
        for (int m = 0; m < 4; ++m) a1[m] = *(const bf8v*)(Wp + (m*16 + l4)*72 + 32 + g4*8);
        #pragma unroll
        for (int m = 0; m < 4; ++m)
            #pragma unroll
            for (int n = 0; n < 4; ++n)
                acc[m][n] = __builtin_amdgcn_mfma_f32_16x16x32_bf16(a0[m], hidW[n], acc[m][n], 0,0,0);
        #pragma unroll
        for (int m = 0; m < 4; ++m)
            #pragma unroll
            for (int n = 0; n < 4; ++n)
                acc[m][n] = __builtin_amdgcn_mfma_f32_16x16x32_bf16(a1[m], hidW[4+n], acc[m][n], 0,0,0);
    }
    {
        float bhid[4];
        #pragma unroll
        for (int n = 0; n < 4; ++n) bhid[n] = b_hid[n*16 + l4];
        #pragma unroll
        for (int m = 0; m < 4; ++m)
            #pragma unroll
            for (int n = 0; n < 4; ++n) {
                f4v q;
                #pragma unroll
                for (int r = 0; r < 4; ++r) q[r] = acc[m][n][r] + bhid[n];
                acc[m][n] = gelu4(q);
            }
    }
    // prefetch xcnn weights (consumed in P3)
    bf8v x1W[8];
    #pragma unroll
    for (int s = 0; s < 2; ++s)
        #pragma unroll
        for (int n = 0; n < 4; ++n)
            x1W[s*4+n] = *(const bf8v*)(wsw + W_X1_OFF + (n*16+l4)*64 + s*32 + g4*8);
    WSYNC();
    #pragma unroll
    for (int m = 0; m < 4; ++m)
        #pragma unroll
        for (int n = 0; n < 4; ++n)
            #pragma unroll
            for (int r = 0; r < 4; ++r)
                Wp[(m*16 + g4*4 + r)*72 + n*16 + l4] = bfr(acc[m][n][r]);
    WSYNC();

    uint32 hidpk[32];   // res = [0..15], gate = [16..31]
    #pragma unroll
    for (int q8 = 0; q8 < 8; ++q8) {
        u4v v = *(const u4v*)(Wp + t*72 + q8*8);
        #pragma unroll
        for (int j = 0; j < 4; ++j) hidpk[q8*4 + j] = v[j];
    }

    // ---------------- P3: xcnn GEMM + bias, per-pixel LN (LDS 3-pass) ----------------
    #pragma unroll
    for (int m = 0; m < 4; ++m)
        #pragma unroll
        for (int n = 0; n < 4; ++n)
            acc[m][n] = (f4v){0.f,0.f,0.f,0.f};
    {
        bf8v a0[4], a1[4];
        #pragma unroll
        for (int m = 0; m < 4; ++m) a0[m] = *(const bf8v*)(Wp + (m*16 + l4)*72 + g4*8);
        #pragma unroll
        for (int m = 0; m < 4; ++m) a1[m] = *(const bf8v*)(Wp + (m*16 + l4)*72 + 32 + g4*8);
        #pragma unroll
        for (int m = 0; m < 4; ++m)
            #pragma unroll
            for (int n = 0; n < 4; ++n)
                acc[m][n] = __builtin_amdgcn_mfma_f32_16x16x32_bf16(a0[m], x1W[n], acc[m][n], 0,0,0);
        #pragma unroll
        for (int m = 0; m < 4; ++m)
            #pragma unroll
            for (int n = 0; n < 4; ++n)
                acc[m][n] = __builtin_amdgcn_mfma_f32_16x16x32_bf16(a1[m], x1W[4+n], acc[m][n], 0,0,0);
    }
    {
        float bx[4];
        #pragma unroll
        for (int n = 0; n < 4; ++n) bx[n] = xcnn_b1[n*16 + l4];
        #pragma unroll
        for (int m = 0; m < 4; ++m)
            #pragma unroll
            for (int n = 0; n < 4; ++n)
                #pragma unroll
                for (int r = 0; r < 4; ++r)
                    acc[m][n][r] += bx[n];
    }
    // prefetch proj weights (consumed in P4.5, after the long P4 phase)
    bf8v projW[4];
    #pragma unroll
    for (int s = 0; s < 2; ++s)
        #pragma unroll
        for (int n = 0; n < 2; ++n)
            projW[s*2+n] = *(const bf8v*)(wsw + W_PROJ_OFF + (n*16+l4)*64 + s*32 + g4*8);
    WSYNC();
    #pragma unroll
    for (int m = 0; m < 4; ++m)
        #pragma unroll
        for (int n = 0; n < 4; ++n)
            #pragma unroll
            for (int r = 0; r < 4; ++r)
                Wp[(m*16 + g4*4 + r)*72 + n*16 + l4] = bfr(acc[m][n][r]);
    WSYNC();
    {   // LN over 64 channels, 3 rolled passes over own row
        float s = 0.f;
        #pragma unroll 1
        for (int q8 = 0; q8 < 8; ++q8) {
            u4v v = *(const u4v*)(Wp + t*72 + q8*8);
            #pragma unroll
            for (int j = 0; j < 4; ++j) s += bl(v[j]) + bh(v[j]);
        }
        float mu = s * (1.f/64.f);
        float s2 = 0.f;
        #pragma unroll 1
        for (int q8 = 0; q8 < 8; ++q8) {
            u4v v = *(const u4v*)(Wp + t*72 + q8*8);
            #pragma unroll
            for (int j = 0; j < 4; ++j) {
                float d0 = bl(v[j]) - mu, d1 = bh(v[j]) - mu;
                s2 = fmaf(d0, d0, fmaf(d1, d1, s2));
            }
        }
        float rstd = rsqrtf(s2*(1.f/64.f) + EPSF);
        #pragma unroll 1
        for (int q8 = 0; q8 < 8; ++q8) {
            u4v v = *(const u4v*)(Wp + t*72 + q8*8);
            u4v w;
            #pragma unroll
            for (int j = 0; j < 4; ++j) {
                int c = q8*8 + 2*j;
                float a = (bl(v[j]) - mu)*rstd*xcnn_ln_w[c]   + xcnn_ln_b[c];
                float b = (bh(v[j]) - mu)*rstd*xcnn_ln_w[c+1] + xcnn_ln_b[c+1];
                w[j] = pk2(a, b);
            }
            *(u4v*)(Wp + t*72 + q8*8) = w;
        }
    }
    WSYNC();

    // ---------------- P4: depthwise 3x3 + gelu (zero-row border, two halves) ----------------
    #pragma unroll 1
    for (int h = 0; h < 2; ++h) {
        float xh[32];
        #pragma unroll
        for (int o = 0; o < 32; ++o) xh[o] = xcnn_dw_b[h*32 + o];
        #pragma unroll 1
        for (int ki = 0; ki < 3; ++ki) {
            #pragma unroll 1
            for (int kj = 0; kj < 3; ++kj) {
                int rr = py + ki - 1, cc = px + kj - 1;
                bool val = ((unsigned)rr < 8u) && ((unsigned)cc < 8u);
                int pnn = val ? rr*8 + cc : 64;
                const unsigned short* rp = Wp + pnn*72 + h*32;
                const float* wp = wf + F_DWT + (ki*3+kj)*64 + h*32;
                #pragma unroll
                for (int c8 = 0; c8 < 4; ++c8) {
                    u4v v = *(const u4v*)(rp + c8*8);
                    #pragma unroll
                    for (int j = 0; j < 4; ++j) {
                        int c = c8*8 + 2*j;
                        xh[c]   = fmaf(bl(v[j]), wp[c],   xh[c]);
                        xh[c+1] = fmaf(bh(v[j]), wp[c+1], xh[c+1]);
                    }
                }
            }
        }
        #pragma unroll
        for (int g = 0; g < 8; ++g) {
            f4v q = (f4v){xh[4*g], xh[4*g+1], xh[4*g+2], xh[4*g+3]};
            q = gelu4(q);
            xh[4*g]=q[0]; xh[4*g+1]=q[1]; xh[4*g+2]=q[2]; xh[4*g+3]=q[3];
        }
        WSYNC();
        #pragma unroll
        for (int c8 = 0; c8 < 4; ++c8) {
            u4v w;
            #pragma unroll
            for (int j = 0; j < 4; ++j) w[j] = pk2(xh[c8*8+2*j], xh[c8*8+2*j+1]);
            *(u4v*)(Wp + t*72 + h*32 + c8*8) = w;
        }
    }
    WSYNC();

    // ---------------- P4.5: channel mean (lane = channel) + proj GEMM ----------------
    float pc;
    {
        float ps = 0.f;
        #pragma unroll 1
        for (int p8 = 0; p8 < 8; ++p8) {
            #pragma unroll
            for (int q = 0; q < 8; ++q) ps += bl((uint32)Wp[(p8*8+q)*72 + t]);
        }
        pc = ps * (1.f/64.f);
    }
    f4v accp[4][2];
    #pragma unroll
    for (int m = 0; m < 4; ++m) { accp[m][0] = (f4v){0.f,0.f,0.f,0.f}; accp[m][1] = (f4v){0.f,0.f,0.f,0.f}; }
    {
        bf8v a0[4], a1[4];
        #pragma unroll
        for (int m = 0; m < 4; ++m) a0[m] = *(const bf8v*)(Wp + (m*16 + l4)*72 + g4*8);
        #pragma unroll
        for (int m = 0; m < 4; ++m) a1[m] = *(const bf8v*)(Wp + (m*16 + l4)*72 + 32 + g4*8);
        #pragma unroll
        for (int m = 0; m < 4; ++m)
            #pragma unroll
            for (int n = 0; n < 2; ++n)
                accp[m][n] = __builtin_amdgcn_mfma_f32_16x16x32_bf16(a0[m], projW[n], accp[m][n], 0,0,0);
        #pragma unroll
        for (int m = 0; m < 4; ++m)
            #pragma unroll
            for (int n = 0; n < 2; ++n)
                accp[m][n] = __builtin_amdgcn_mfma_f32_16x16x32_bf16(a1[m], projW[2+n], accp[m][n], 0,0,0);
    }
    {
        float bp0 = proj_b[l4], bp1 = proj_b[16 + l4];
        #pragma unroll
        for (int m = 0; m < 4; ++m)
            #pragma unroll
            for (int r = 0; r < 4; ++r) { accp[m][0][r] += bp0; accp[m][1][r] += bp1; }
    }
    // prefetch dwb_w0 weights (consumed in P7, after the long P5 phase)
    bf8v dwb0W[2];
    #pragma unroll
    for (int n = 0; n < 2; ++n)
        dwb0W[n] = *(const bf8v*)(wsw + W_DWB0_OFF + (n*16+l4)*32 + g4*8);
    WSYNC();
    #pragma unroll
    for (int m = 0; m < 4; ++m)
        #pragma unroll
        for (int n = 0; n < 2; ++n)
            #pragma unroll
            for (int r = 0; r < 4; ++r)
                Wp[(m*16 + g4*4 + r)*72 + n*16 + l4] = bfr(accp[m][n][r]);
    WSYNC();
    uint32 xppk[16];
    #pragma unroll
    for (int q8 = 0; q8 < 4; ++q8) {
        u4v v = *(const u4v*)(Wp + t*72 + q8*8);
        #pragma unroll
        for (int j = 0; j < 4; ++j) xppk[q8*4 + j] = v[j];
    }

    // ---------------- P5: SE gate (distributed matvec via shfl butterfly) ----------------
    {
        float pt[8];
        {
            f4v wa = *(const f4v*)(wf + F_CI1T + t*8);
            f4v wb = *(const f4v*)(wf + F_CI1T + t*8 + 4);
            #pragma unroll
            for (int m = 0; m < 4; ++m) { pt[m] = wa[m]*pc; pt[4+m] = wb[m]*pc; }
        }
        #pragma unroll
        for (int st = 1; st < 64; st <<= 1)
            #pragma unroll
            for (int m = 0; m < 8; ++m) pt[m] += __shfl_xor(pt[m], st, 64);
        float t8[8];
        #pragma unroll
        for (int m = 0; m < 8; ++m) t8[m] = pt[m] + ci_b1[m];
        float s = 0.f;
        #pragma unroll
        for (int m = 0; m < 8; ++m) s += t8[m];
        float mu = s * 0.125f;
        float q2 = 0.f;
        #pragma unroll
        for (int m = 0; m < 8; ++m) { float d = t8[m]-mu; q2 = fmaf(d,d,q2); }
        float rstd = rsqrtf(q2*0.125f + EPSF);
        #pragma unroll
        for (int m = 0; m < 8; ++m) t8[m] = (t8[m]-mu)*rstd*ci_ln_w[m] + ci_ln_b[m];
        f4v qa = gelu4((f4v){t8[0],t8[1],t8[2],t8[3]});
        f4v qb = gelu4((f4v){t8[4],t8[5],t8[6],t8[7]});
        t8[0]=qa[0]; t8[1]=qa[1]; t8[2]=qa[2]; t8[3]=qa[3];
        t8[4]=qb[0]; t8[5]=qb[1]; t8[6]=qb[2]; t8[7]=qb[3];
        if (t < 32) {
            float a = ci_b2[t];
            #pragma unroll
            for (int m = 0; m < 8; ++m) a = fmaf(wf[F_CI2T + m*32 + t], t8[m], a);
            segate_s[wid][t] = sigm(a);
        }
    }
    WSYNC();
    float sg[32];
    #pragma unroll
    for (int g = 0; g < 8; ++g) {
        f4v e = *(const f4v*)&segate_s[wid][g*4];
        #pragma unroll
        for (int r = 0; r < 4; ++r) {
            int o = g*4 + r;
            uint32 pkv = hidpk[16 + o/2];
            float gv = (o & 1) ? bh(pkv) : bl(pkv);
            sg[o] = gv * e[r];
        }
    }
    {   // SGU LayerNorm over 32
        float s = 0.f;
        #pragma unroll
        for (int o = 0; o < 32; ++o) s += sg[o];
        float mu = s * (1.f/32.f);
        float q2 = 0.f;
        #pragma unroll
        for (int o = 0; o < 32; ++o) { float d = sg[o]-mu; q2 = fmaf(d,d,q2); }
        float rstd = rsqrtf(q2*(1.f/32.f) + EPSF);
        #pragma unroll
        for (int o = 0; o < 32; ++o) sg[o] = (sg[o]-mu)*rstd*sgu_ln_w[o] + sgu_ln_b[o];
    }
    WSYNC();
    #pragma unroll
    for (int c8 = 0; c8 < 4; ++c8) {
        u4v w;
        #pragma unroll
        for (int j = 0; j < 4; ++j) w[j] = pk2(sg[c8*8+2*j], sg[c8*8+2*j+1]);
        *(u4v*)(Wp + t*72 + c8*8) = w;
    }
    WSYNC();

    // ---------------- P7: dwb_w0 GEMM -> write g1 TRANSPOSED (Gt, cols 32..63) ----------------
    bf8v dwb2W[2];
    {
        f4v accg[4][2];
        #pragma unroll
        for (int m = 0; m < 4; ++m) { accg[m][0] = (f4v){0.f,0.f,0.f,0.f}; accg[m][1] = (f4v){0.f,0.f,0.f,0.f}; }
        bf8v av[4];
        #pragma unroll
        for (int m = 0; m < 4; ++m) av[m] = *(const bf8v*)(Wp + (m*16 + l4)*72 + g4*8);
        #pragma unroll
        for (int m = 0; m < 4; ++m)
            #pragma unroll
            for (int n = 0; n < 2; ++n)
                accg[m][n] = __builtin_amdgcn_mfma_f32_16x16x32_bf16(av[m], dwb0W[n], accg[m][n], 0,0,0);
        // prefetch dwb_w2 weights (consumed in P9, after the long P8 phase)
        #pragma unroll
        for (int n = 0; n < 2; ++n)
            dwb2W[n] = *(const bf8v*)(wsw + W_DWB2_OFF + (n*16+l4)*32 + g4*8);
        WSYNC();
        #pragma unroll
        for (int m = 0; m < 4; ++m)
            #pragma unroll
            for (int n = 0; n < 2; ++n)
                #pragma unroll
                for (int r = 0; r < 4; ++r) {
                    int q = m*16 + g4*4 + r;
                    Wp[((q>>5)*32 + n*16 + l4)*72 + 32 + (q & 31)] = bfr(accg[m][n][r]);
                }
    }
    WSYNC();

    // ---------------- P8: idw kernel gen + dynamic 7x7 via MFMA (K-split M build) ----------------
    float t8b[8];
    #pragma unroll
    for (int m = 0; m < 8; ++m) t8b[m] = idw_b1[m];
    #pragma unroll 1
    for (int c = 0; c < 32; ++c) {      // g1 row t = Gt column t
        float gv = bl((uint32)Wp[((t>>5)*32 + c)*72 + 32 + (t & 31)]);
        #pragma unroll
        for (int m = 0; m < 8; ++m) t8b[m] = fmaf(wf[F_IW1T + c*8 + m], gv, t8b[m]);
    }
    #pragma unroll
    for (int m = 0; m < 8; ++m)
        t8b[m] = fmaxf(t8b[m]*(idw_bn_w[m]*0.9999950000374997f) + idw_bn_b[m], 0.f);

    f4v accd[4][2];
    #pragma unroll
    for (int m = 0; m < 4; ++m) { accd[m][0] = (f4v){0.f,0.f,0.f,0.f}; accd[m][1] = (f4v){0.f,0.f,0.f,0.f}; }
    #pragma unroll 1
    for (int s = 0; s < 2; ++s) {
        WSYNC();
        #pragma unroll
        for (int i = 0; i < 4; ++i) *(u4v*)(Wp + t*72 + i*8) = (u4v){0,0,0,0};
        #pragma unroll 1
        for (int ki = 0; ki < 7; ++ki) {
            int rr = py + ki - 3;
            #pragma unroll 1
            for (int kj = 0; kj < 7; ++kj) {
                int cc = px + kj - 3;
                int k  = ki*7 + kj;
                float wk = idw_b2[k];
                #pragma unroll
                for (int m = 0; m < 8; ++m) wk = fmaf(idw_w2[k*8 + m], t8b[m], wk);
                int q = rr*8 + cc;
                if (((unsigned)rr < 8u) && ((unsigned)cc < 8u) && ((q >> 5) == s))
                    Wp[t*72 + (q & 31)] = bfr(wk);
            }
        }
        WSYNC();
        bf8v aM[4], bG[2];
        #pragma unroll
        for (int m = 0; m < 4; ++m) aM[m] = *(const bf8v*)(Wp + (m*16 + l4)*72 + g4*8);
        #pragma unroll
        for (int n = 0; n < 2; ++n) bG[n] = *(const bf8v*)(Wp + (s*32 + n*16 + l4)*72 + 32 + g4*8);
        #pragma unroll
        for (int m = 0; m < 4; ++m)
            #pragma unroll
            for (int n = 0; n < 2; ++n)
                accd[m][n] = __builtin_amdgcn_mfma_f32_16x16x32_bf16(aM[m], bG[n], accd[m][n], 0,0,0);
    }
    WSYNC();
    #pragma unroll
    for (int m = 0; m < 4; ++m)
        #pragma unroll
        for (int n = 0; n < 2; ++n)
            #pragma unroll
            for (int r = 0; r < 4; ++r)
                Wp[(m*16 + g4*4 + r)*72 + n*16 + l4] = bfr(accd[m][n][r]);
    WSYNC();

    // ---------------- P9: dwb_w2 GEMM -> sgu = g2 * res ----------------
    bf8v outW[8];
    {
        f4v accg[4][2];
        #pragma unroll
        for (int m = 0; m < 4; ++m) { accg[m][0] = (f4v){0.f,0.f,0.f,0.f}; accg[m][1] = (f4v){0.f,0.f,0.f,0.f}; }
        bf8v av[4];
        #pragma unroll
        for (int m = 0; m < 4; ++m) av[m] = *(const bf8v*)(Wp + (m*16 + l4)*72 + g4*8);
        #pragma unroll
        for (int m = 0; m < 4; ++m)
            #pragma unroll
            for (int n = 0; n < 2; ++n)
                accg[m][n] = __builtin_amdgcn_mfma_f32_16x16x32_bf16(av[m], dwb2W[n], accg[m][n], 0,0,0);
        // prefetch out weights (consumed in P11, after the P10 phase)
        #pragma unroll
        for (int s = 0; s < 2; ++s)
            #pragma unroll
            for (int n = 0; n < 4; ++n)
                outW[s*4+n] = *(const bf8v*)(wsw + W_OUT_OFF + (n*16+l4)*64 + s*32 + g4*8);
        WSYNC();
        #pragma unroll
        for (int m = 0; m < 4; ++m)
            #pragma unroll
            for (int n = 0; n < 2; ++n)
                #pragma unroll
                for (int r = 0; r < 4; ++r)
                    Wp[(m*16 + g4*4 + r)*72 + n*16 + l4] = bfr(accg[m][n][r]);
        WSYNC();
    }
    float sgu[32];
    #pragma unroll
    for (int q8 = 0; q8 < 4; ++q8) {
        u4v v = *(const u4v*)(Wp + t*72 + q8*8);
        #pragma unroll
        for (int j = 0; j < 4; ++j) {
            int q = q8*4 + j;
            sgu[2*q]   = bl(v[j]) * bl(hidpk[q]);
            sgu[2*q+1] = bh(v[j]) * bh(hidpk[q]);
        }
    }
    WSYNC();

    // ---------------- P10: stage sgu (cols 32..63), si gate, stage xp*siv ----------------
    #pragma unroll
    for (int c8 = 0; c8 < 4; ++c8) {
        u4v w;
        #pragma unroll
        for (int j = 0; j < 4; ++j) w[j] = pk2(sgu[c8*8+2*j], sgu[c8*8+2*j+1]);
        *(u4v*)(Wp + t*72 + 32 + c8*8) = w;
    }
    WSYNC();
    float siv;
    {
        float s1[4];
        #pragma unroll
        for (int m = 0; m < 4; ++m) s1[m] = si_b1[m];
        #pragma unroll 1
        for (int c8 = 0; c8 < 4; ++c8) {
            u4v v = *(const u4v*)(Wp + t*72 + 32 + c8*8);
            #pragma unroll
            for (int j = 0; j < 4; ++j) {
                int c = c8*8 + 2*j;
                float a0 = bl(v[j]), a1 = bh(v[j]);
                #pragma unroll
                for (int m = 0; m < 4; ++m) {
                    s1[m] = fmaf(wf[F_SI1T + c*4 + m],     a0, s1[m]);
                    s1[m] = fmaf(wf[F_SI1T + (c+1)*4 + m], a1, s1[m]);
                }
            }
        }
        float s = s1[0]+s1[1]+s1[2]+s1[3];
        float mu = s * 0.25f;
        float q2 = 0.f;
        #pragma unroll
        for (int m = 0; m < 4; ++m) { float d = s1[m]-mu; q2 = fmaf(d,d,q2); }
        float rstd = rsqrtf(q2*0.25f + EPSF);
        f4v q;
        #pragma unroll
        for (int m = 0; m < 4; ++m) q[m] = (s1[m]-mu)*rstd*si_ln_w[m] + si_ln_b[m];
        q = gelu4(q);
        float a = si_b2[0];
        #pragma unroll
        for (int m = 0; m < 4; ++m) a = fmaf(si_w2[m], q[m], a);
        siv = sigm(a);
    }
    #pragma unroll
    for (int c8 = 0; c8 < 4; ++c8) {
        u4v w;
        #pragma unroll
        for (int j = 0; j < 4; ++j) {
            int q = c8*4 + j;
            w[j] = pk2(bl(xppk[q])*siv, bh(xppk[q])*siv);
        }
        *(u4v*)(Wp + t*72 + c8*8) = w;
    }
    WSYNC();

    // ---------------- P11: out GEMM + bias ----------------
    #pragma unroll
    for (int m = 0; m < 4; ++m)
        #pragma unroll
        for (int n = 0; n < 4; ++n)
            acc[m][n] = (f4v){0.f,0.f,0.f,0.f};
    {
        bf8v a0[4], a1[4];
        #pragma unroll
        for (int m = 0; m < 4; ++m) a0[m] = *(const bf8v*)(Wp + (m*16 + l4)*72 + g4*8);
        #pragma unroll
        for (int m = 0; m < 4; ++m) a1[m] = *(const bf8v*)(Wp + (m*16 + l4)*72 + 32 + g4*8);
        #pragma unroll
        for (int m = 0; m < 4; ++m)
            #pragma unroll
            for (int n = 0; n < 4; ++n)
                acc[m][n] = __builtin_amdgcn_mfma_f32_16x16x32_bf16(a0[m], outW[n], acc[m][n], 0,0,0);
        #pragma unroll
        for (int m = 0; m < 4; ++m)
            #pragma unroll
            for (int n = 0; n < 4; ++n)
                acc[m][n] = __builtin_amdgcn_mfma_f32_16x16x32_bf16(a1[m], outW[4+n], acc[m][n], 0,0,0);
    }
    {
        float bo[4];
        #pragma unroll
        for (int n = 0; n < 4; ++n) bo[n] = out_b[n*16 + l4];
        #pragma unroll
        for (int m = 0; m < 4; ++m)
            #pragma unroll
            for (int n = 0; n < 4; ++n)
                #pragma unroll
                for (int r = 0; r < 4; ++r)
                    acc[m][n][r] += bo[n];
    }
    WSYNC();
    #pragma unroll
    for (int m = 0; m < 4; ++m)
        #pragma unroll
        for (int n = 0; n < 4; ++n)
            #pragma unroll
            for (int r = 0; r < 4; ++r)
                Wp[(m*16 + g4*4 + r)*72 + n*16 + l4] = bfr(acc[m][n][r]);
    __syncthreads();

    // ---------------- P12: cooperative coalesced store (nontemporal) ----------------
    {
        float* obase = out + (bb*64)*HWSZ + (ph*8)*256 + strip*32;
        const unsigned short* lsrc = bufS + lp*PSTR + (ty*8 + lpx)*72;
        #pragma unroll 1
        for (int c8 = 0; c8 < 8; ++c8) {
            u4v v = *(const u4v*)(lsrc + c8*8);
            #pragma unroll
            for (int j = 0; j < 4; ++j) {
                int c = c8*8 + 2*j;
                __builtin_nontemporal_store(bl(v[j]), obase + c*HWSZ + yx);
                __builtin_nontemporal_store(bh(v[j]), obase + (c+1)*HWSZ + yx);
            }
        }
    }
}

extern "C" void kernel_launch(void* const* d_in, const int* in_sizes, int n_in,
                              void* d_out, int out_size, void* d_ws, size_t ws_size,
                              hipStream_t stream) {
    const float* p[35];
    for (int i = 0; i < 35; ++i) p[i] = (const float*)d_in[i];
    unsigned short* ws = (unsigned short*)d_ws;
    float* wsf = (float*)ws + 8192;

    prep_w<<<64, 256, 0, stream>>>(p[1], p[3], p[21], p[23], p[27], p[34], ws);
    prep_t<<<7, 256, 0, stream>>>(p[7], p[9], p[13], p[28], p[15], wsf);

    const int B = in_sizes[0] / (64 * 256 * 256);   // = 4
    dim3 grid(B * 32 * 8), block(256);
    gmlp_fused<<<grid, block, 0, stream>>>(
        p[0],  p[2],  p[4],  p[5],  p[6],  p[8],
        p[10], p[11], p[12], p[14],
        p[16], p[17], p[18], p[19], p[20],
        p[22], p[24], p[25], p[26],
        p[29], p[30], p[31], p[32], p[33],
        ws, (float*)d_out);
}

// Round 15
// 84.765 us; speedup vs baseline: 1.6913x; 1.0003x over previous
//
#include <hip/hip_runtime.h>
#include <math.h>

#define HWSZ 65536
#define EPSF 1e-5f
#define PSTR 4680   // shorts per patch LDS region: 65 rows * 72 (row 64 = zeros)

typedef __attribute__((ext_vector_type(8))) short bf8v;
typedef __attribute__((ext_vector_type(4))) float f4v;
typedef __attribute__((ext_vector_type(4))) unsigned int u4v;
typedef unsigned int uint32;

// bf16 ws offsets (shorts)
#define W_HID_OFF   0
#define W_X1_OFF    4096
#define W_PROJ_OFF  8192
#define W_OUT_OFF   10240
#define W_DWB0_OFF  14336
#define W_DWB2_OFF  15360
// f32 ws region starts at float index 8192
#define F_DWT   0
#define F_CI1T  576
#define F_CI2T  1088
#define F_IW1T  1344
#define F_SI1T  1600

__device__ __forceinline__ float bl(uint32 u){ return __uint_as_float(u<<16); }
__device__ __forceinline__ float bh(uint32 u){ return __uint_as_float(u & 0xffff0000u); }
__device__ __forceinline__ uint32 pk2(float a, float b){
  uint32 r; asm("v_cvt_pk_bf16_f32 %0, %1, %2" : "=v"(r) : "v"(a), "v"(b)); return r;
}
// NOTE (R14 post-mortem): do NOT replace bfr with (ushort)pk2(x,x) on C-write
// paths — v_cvt_pk_bf16_f32 is not RNE-equivalent there (R7/R14 both failed).
__device__ __forceinline__ unsigned short bfr(float x){
  uint32 u = __float_as_uint(x); u += 0x7fffu + ((u>>16)&1u); return (unsigned short)(u>>16);
}
__device__ __forceinline__ float rcp_f(float x){ float r; asm("v_rcp_f32 %0, %1" : "=v"(r) : "v"(x)); return r; }
__device__ __forceinline__ float exp2_f(float x){ float r; asm("v_exp_f32 %0, %1" : "=v"(r) : "v"(x)); return r; }
__device__ __forceinline__ float sigm(float v){
  return rcp_f(1.0f + exp2_f(v * -1.4426950408889634f));
}

// fast gelu: x * sigmoid(1.702 x)  (max |err| ~0.02, within absmax budget)
__device__ __forceinline__ f4v gelu4(f4v v){
  f4v r;
  #pragma unroll
  for (int i=0;i<4;++i){
    float x = v[i];
    r[i] = x * rcp_f(1.0f + exp2_f(x * -2.4554669596f));  // 1.702*log2(e)
  }
  return r;
}

// wave-local LDS fence: waits lgkmcnt only (in-flight VMEM loads cross it)
#define WSYNC() asm volatile("s_waitcnt lgkmcnt(0)" ::: "memory")

__global__ void prep_w(const float* __restrict__ a0, const float* __restrict__ a1,
                       const float* __restrict__ a2, const float* __restrict__ a3,
                       const float* __restrict__ a4, const float* __restrict__ a5,
                       unsigned short* __restrict__ ws){
  int i = blockIdx.x*256 + threadIdx.x;
  if (i >= 16384) return;
  float v;
  if      (i < 4096)  v = a0[i];
  else if (i < 8192)  v = a1[i-4096];
  else if (i < 10240) v = a2[i-8192];
  else if (i < 14336) v = a3[i-10240];
  else if (i < 15360) v = a4[i-14336];
  else                v = a5[i-15360];
  ws[i] = bfr(v);
}

__global__ void prep_t(const float* __restrict__ dw, const float* __restrict__ ci1,
                       const float* __restrict__ ci2, const float* __restrict__ iw1,
                       const float* __restrict__ sw1, float* __restrict__ wf){
  int i = blockIdx.x*256 + threadIdx.x;
  if (i >= 1728) return;
  float v;
  if (i < 576)        { int k=i/64, c=i%64;            v = dw[c*9+k]; }
  else if (i < 1088)  { int j=i-576,  c=j/8, m=j%8;    v = ci1[m*64+c]; }
  else if (i < 1344)  { int j=i-1088, m=j/32, o=j%32;  v = ci2[o*8+m]; }
  else if (i < 1600)  { int j=i-1344, c=j/8, m=j%8;    v = iw1[m*32+c]; }
  else                { int j=i-1600, c=j/4, m=j%4;    v = sw1[m*32+c]; }
  wf[i] = v;
}

__global__ __launch_bounds__(256, 4)
void gmlp_fused(const float* __restrict__ x,
                const float* __restrict__ b_hid,
                const float* __restrict__ xcnn_b1,
                const float* __restrict__ xcnn_ln_w, const float* __restrict__ xcnn_ln_b,
                const float* __restrict__ xcnn_dw_b,
                const float* __restrict__ ci_b1,
                const float* __restrict__ ci_ln_w, const float* __restrict__ ci_ln_b,
                const float* __restrict__ ci_b2,
                const float* __restrict__ si_b1,
                const float* __restrict__ si_ln_w, const float* __restrict__ si_ln_b,
                const float* __restrict__ si_w2,   const float* __restrict__ si_b2,
                const float* __restrict__ proj_b,
                const float* __restrict__ out_b,
                const float* __restrict__ sgu_ln_w, const float* __restrict__ sgu_ln_b,
                const float* __restrict__ idw_b1,
                const float* __restrict__ idw_bn_w, const float* __restrict__ idw_bn_b,
                const float* __restrict__ idw_w2,  const float* __restrict__ idw_b2,
                const unsigned short* __restrict__ wsw,
                float* __restrict__ out)
{
    __shared__ __align__(16) unsigned short bufS[4*PSTR];
    __shared__ __align__(16) float segate_s[4][32];

    const float* wf = (const float*)wsw + 8192;

    const int tx  = threadIdx.x;
    const int wid = tx >> 6;
    const int t   = tx & 63;
    const int l4  = t & 15, g4 = t >> 4;
    const int py  = t >> 3,  px = t & 7;

    const int bid   = blockIdx.x;     // grid = B * 32 * 8
    const int strip = bid & 7;
    const int ph    = (bid >> 3) & 31;
    const int bb    = bid >> 8;

    unsigned short* Wp = bufS + wid*PSTR;

    const int ty  = tx >> 5;
    const int txx = tx & 31;
    const int lp  = txx >> 3;
    const int lpx = txx & 7;
    const int yx  = ty*256 + txx;
    const float* xbase = x + (bb*64)*HWSZ + (ph*8)*256 + strip*32;
    unsigned short* ldst = bufS + lp*PSTR + (ty*8 + lpx)*72;

    // ---------------- P1: cooperative coalesced load + zero-row + hidW prefetch ----------------
    #pragma unroll 1
    for (int c8 = 0; c8 < 8; ++c8) {
        u4v w;
        #pragma unroll
        for (int j = 0; j < 4; ++j) {
            int c = c8*8 + 2*j;
            float a = __builtin_nontemporal_load(xbase + c*HWSZ + yx);
            float b = __builtin_nontemporal_load(xbase + (c+1)*HWSZ + yx);
            w[j] = pk2(a, b);
        }
        *(u4v*)(ldst + c8*8) = w;
    }
    if (t < 9) *(u4v*)(Wp + 64*72 + t*8) = (u4v){0,0,0,0};   // row 64 = zeros
    // prefetch hidden weights (consumed in P2; cover = barrier + ds_reads)
    bf8v hidW[8];
    #pragma unroll
    for (int s = 0; s < 2; ++s)
        #pragma unroll
        for (int n = 0; n < 4; ++n)
            hidW[s*4+n] = *(const bf8v*)(wsw + W_HID_OFF + (n*16+l4)*64 + s*32 + g4*8);
    __syncthreads();

    // ---------------- P2: hidden GEMM + bias + gelu ----------------
    f4v acc[4][4];
    #pragma unroll
    for (int m = 0; m < 4; ++m)
        #pragma unroll
        for (int n = 0; n < 4; ++n)
            acc[m][n] = (f4v){0.f,0.f,0.f,0.f};
    {
        bf8v a0[4], a1[4];
        #pragma unroll
        for (int m = 0; m < 4; ++m) a0[m] = *(const bf8v*)(Wp + (m*16 + l4)*72 + g4*8);
        #pragma unroll
        for (int m = 0; m < 4; ++m) a1[m] = *(const bf8v*)(Wp + (m*16 + l4)*72 + 32 + g4*8);
        #pragma unroll
        for (int m = 0; m < 4; ++m)
            #pragma unroll
            for (int n = 0; n < 4; ++n)
                acc[m][n] = __builtin_amdgcn_mfma_f32_16x16x32_bf16(a0[m], hidW[n], acc[m][n], 0,0,0);
        #pragma unroll
        for (int m = 0; m < 4; ++m)
            #pragma unroll
            for (int n = 0; n < 4; ++n)
                acc[m][n] = __builtin_amdgcn_mfma_f32_16x16x32_bf16(a1[m], hidW[4+n], acc[m][n], 0,0,0);
    }
    {
        float bhid[4];
        #pragma unroll
        for (int n = 0; n < 4; ++n) bhid[n] = b_hid[n*16 + l4];
        #pragma unroll
        for (int m = 0; m < 4; ++m)
            #pragma unroll
            for (int n = 0; n < 4; ++n) {
                f4v q;
                #pragma unroll
                for (int r = 0; r < 4; ++r) q[r] = acc[m][n][r] + bhid[n];
                acc[m][n] = gelu4(q);
            }
    }
    // prefetch xcnn weights (consumed in P3)
    bf8v x1W[8];
    #pragma unroll
    for (int s = 0; s < 2; ++s)
        #pragma unroll
        for (int n = 0; n < 4; ++n)
            x1W[s*4+n] = *(const bf8v*)(wsw + W_X1_OFF + (n*16+l4)*64 + s*32 + g4*8);
    WSYNC();
    #pragma unroll
    for (int m = 0; m < 4; ++m)
        #pragma unroll
        for (int n = 0; n < 4; ++n)
            #pragma unroll
            for (int r = 0; r < 4; ++r)
                Wp[(m*16 + g4*4 + r)*72 + n*16 + l4] = bfr(acc[m][n][r]);
    WSYNC();

    uint32 hidpk[32];   // res = [0..15], gate = [16..31]
    #pragma unroll
    for (int q8 = 0; q8 < 8; ++q8) {
        u4v v = *(const u4v*)(Wp + t*72 + q8*8);
        #pragma unroll
        for (int j = 0; j < 4; ++j) hidpk[q8*4 + j] = v[j];
    }

    // ---------------- P3: xcnn GEMM + bias, per-pixel LN (LDS 3-pass) ----------------
    #pragma unroll
    for (int m = 0; m < 4; ++m)
        #pragma unroll
        for (int n = 0; n < 4; ++n)
            acc[m][n] = (f4v){0.f,0.f,0.f,0.f};
    {
        bf8v a0[4], a1[4];
        #pragma unroll
        for (int m = 0; m < 4; ++m) a0[m] = *(const bf8v*)(Wp + (m*16 + l4)*72 + g4*8);
        #pragma unroll
        for (int m = 0; m < 4; ++m) a1[m] = *(const bf8v*)(Wp + (m*16 + l4)*72 + 32 + g4*8);
        #pragma unroll
        for (int m = 0; m < 4; ++m)
            #pragma unroll
            for (int n = 0; n < 4; ++n)
                acc[m][n] = __builtin_amdgcn_mfma_f32_16x16x32_bf16(a0[m], x1W[n], acc[m][n], 0,0,0);
        #pragma unroll
        for (int m = 0; m < 4; ++m)
            #pragma unroll
            for (int n = 0; n < 4; ++n)
                acc[m][n] = __builtin_amdgcn_mfma_f32_16x16x32_bf16(a1[m], x1W[4+n], acc[m][n], 0,0,0);
    }
    {
        float bx[4];
        #pragma unroll
        for (int n = 0; n < 4; ++n) bx[n] = xcnn_b1[n*16 + l4];
        #pragma unroll
        for (int m = 0; m < 4; ++m)
            #pragma unroll
            for (int n = 0; n < 4; ++n)
                #pragma unroll
                for (int r = 0; r < 4; ++r)
                    acc[m][n][r] += bx[n];
    }
    // prefetch proj weights (consumed in P4.5, after the long P4 phase)
    bf8v projW[4];
    #pragma unroll
    for (int s = 0; s < 2; ++s)
        #pragma unroll
        for (int n = 0; n < 2; ++n)
            projW[s*2+n] = *(const bf8v*)(wsw + W_PROJ_OFF + (n*16+l4)*64 + s*32 + g4*8);
    WSYNC();
    #pragma unroll
    for (int m = 0; m < 4; ++m)
        #pragma unroll
        for (int n = 0; n < 4; ++n)
            #pragma unroll
            for (int r = 0; r < 4; ++r)
                Wp[(m*16 + g4*4 + r)*72 + n*16 + l4] = bfr(acc[m][n][r]);
    WSYNC();
    {   // LN over 64 channels, 3 rolled passes over own row
        float s = 0.f;
        #pragma unroll 1
        for (int q8 = 0; q8 < 8; ++q8) {
            u4v v = *(const u4v*)(Wp + t*72 + q8*8);
            #pragma unroll
            for (int j = 0; j < 4; ++j) s += bl(v[j]) + bh(v[j]);
        }
        float mu = s * (1.f/64.f);
        float s2 = 0.f;
        #pragma unroll 1
        for (int q8 = 0; q8 < 8; ++q8) {
            u4v v = *(const u4v*)(Wp + t*72 + q8*8);
            #pragma unroll
            for (int j = 0; j < 4; ++j) {
                float d0 = bl(v[j]) - mu, d1 = bh(v[j]) - mu;
                s2 = fmaf(d0, d0, fmaf(d1, d1, s2));
            }
        }
        float rstd = rsqrtf(s2*(1.f/64.f) + EPSF);
        #pragma unroll 1
        for (int q8 = 0; q8 < 8; ++q8) {
            u4v v = *(const u4v*)(Wp + t*72 + q8*8);
            u4v w;
            #pragma unroll
            for (int j = 0; j < 4; ++j) {
                int c = q8*8 + 2*j;
                float a = (bl(v[j]) - mu)*rstd*xcnn_ln_w[c]   + xcnn_ln_b[c];
                float b = (bh(v[j]) - mu)*rstd*xcnn_ln_w[c+1] + xcnn_ln_b[c+1];
                w[j] = pk2(a, b);
            }
            *(u4v*)(Wp + t*72 + q8*8) = w;
        }
    }
    WSYNC();

    // ---------------- P4: depthwise 3x3 + gelu (zero-row border, two halves) ----------------
    #pragma unroll 1
    for (int h = 0; h < 2; ++h) {
        float xh[32];
        #pragma unroll
        for (int o = 0; o < 32; ++o) xh[o] = xcnn_dw_b[h*32 + o];
        #pragma unroll 1
        for (int ki = 0; ki < 3; ++ki) {
            #pragma unroll 1
            for (int kj = 0; kj < 3; ++kj) {
                int rr = py + ki - 1, cc = px + kj - 1;
                bool val = ((unsigned)rr < 8u) && ((unsigned)cc < 8u);
                int pnn = val ? rr*8 + cc : 64;
                const unsigned short* rp = Wp + pnn*72 + h*32;
                const float* wp = wf + F_DWT + (ki*3+kj)*64 + h*32;
                #pragma unroll
                for (int c8 = 0; c8 < 4; ++c8) {
                    u4v v = *(const u4v*)(rp + c8*8);
                    #pragma unroll
                    for (int j = 0; j < 4; ++j) {
                        int c = c8*8 + 2*j;
                        xh[c]   = fmaf(bl(v[j]), wp[c],   xh[c]);
                        xh[c+1] = fmaf(bh(v[j]), wp[c+1], xh[c+1]);
                    }
                }
            }
        }
        #pragma unroll
        for (int g = 0; g < 8; ++g) {
            f4v q = (f4v){xh[4*g], xh[4*g+1], xh[4*g+2], xh[4*g+3]};
            q = gelu4(q);
            xh[4*g]=q[0]; xh[4*g+1]=q[1]; xh[4*g+2]=q[2]; xh[4*g+3]=q[3];
        }
        WSYNC();
        #pragma unroll
        for (int c8 = 0; c8 < 4; ++c8) {
            u4v w;
            #pragma unroll
            for (int j = 0; j < 4; ++j) w[j] = pk2(xh[c8*8+2*j], xh[c8*8+2*j+1]);
            *(u4v*)(Wp + t*72 + h*32 + c8*8) = w;
        }
    }
    WSYNC();

    // ---------------- P4.5: channel mean (lane = channel) + proj GEMM ----------------
    float pc;
    {
        float ps = 0.f;
        #pragma unroll 1
        for (int p8 = 0; p8 < 8; ++p8) {
            #pragma unroll
            for (int q = 0; q < 8; ++q) ps += bl((uint32)Wp[(p8*8+q)*72 + t]);
        }
        pc = ps * (1.f/64.f);
    }
    f4v accp[4][2];
    #pragma unroll
    for (int m = 0; m < 4; ++m) { accp[m][0] = (f4v){0.f,0.f,0.f,0.f}; accp[m][1] = (f4v){0.f,0.f,0.f,0.f}; }
    {
        bf8v a0[4], a1[4];
        #pragma unroll
        for (int m = 0; m < 4; ++m) a0[m] = *(const bf8v*)(Wp + (m*16 + l4)*72 + g4*8);
        #pragma unroll
        for (int m = 0; m < 4; ++m) a1[m] = *(const bf8v*)(Wp + (m*16 + l4)*72 + 32 + g4*8);
        #pragma unroll
        for (int m = 0; m < 4; ++m)
            #pragma unroll
            for (int n = 0; n < 2; ++n)
                accp[m][n] = __builtin_amdgcn_mfma_f32_16x16x32_bf16(a0[m], projW[n], accp[m][n], 0,0,0);
        #pragma unroll
        for (int m = 0; m < 4; ++m)
            #pragma unroll
            for (int n = 0; n < 2; ++n)
                accp[m][n] = __builtin_amdgcn_mfma_f32_16x16x32_bf16(a1[m], projW[2+n], accp[m][n], 0,0,0);
    }
    {
        float bp0 = proj_b[l4], bp1 = proj_b[16 + l4];
        #pragma unroll
        for (int m = 0; m < 4; ++m)
            #pragma unroll
            for (int r = 0; r < 4; ++r) { accp[m][0][r] += bp0; accp[m][1][r] += bp1; }
    }
    // prefetch dwb_w0 weights (consumed in P7, after the long P5 phase)
    bf8v dwb0W[2];
    #pragma unroll
    for (int n = 0; n < 2; ++n)
        dwb0W[n] = *(const bf8v*)(wsw + W_DWB0_OFF + (n*16+l4)*32 + g4*8);
    WSYNC();
    #pragma unroll
    for (int m = 0; m < 4; ++m)
        #pragma unroll
        for (int n = 0; n < 2; ++n)
            #pragma unroll
            for (int r = 0; r < 4; ++r)
                Wp[(m*16 + g4*4 + r)*72 + n*16 + l4] = bfr(accp[m][n][r]);
    WSYNC();
    uint32 xppk[16];
    #pragma unroll
    for (int q8 = 0; q8 < 4; ++q8) {
        u4v v = *(const u4v*)(Wp + t*72 + q8*8);
        #pragma unroll
        for (int j = 0; j < 4; ++j) xppk[q8*4 + j] = v[j];
    }

    // ---------------- P5: SE gate (distributed matvec via shfl butterfly) ----------------
    {
        float pt[8];
        {
            f4v wa = *(const f4v*)(wf + F_CI1T + t*8);
            f4v wb = *(const f4v*)(wf + F_CI1T + t*8 + 4);
            #pragma unroll
            for (int m = 0; m < 4; ++m) { pt[m] = wa[m]*pc; pt[4+m] = wb[m]*pc; }
        }
        #pragma unroll
        for (int st = 1; st < 64; st <<= 1)
            #pragma unroll
            for (int m = 0; m < 8; ++m) pt[m] += __shfl_xor(pt[m], st, 64);
        float t8[8];
        #pragma unroll
        for (int m = 0; m < 8; ++m) t8[m] = pt[m] + ci_b1[m];
        float s = 0.f;
        #pragma unroll
        for (int m = 0; m < 8; ++m) s += t8[m];
        float mu = s * 0.125f;
        float q2 = 0.f;
        #pragma unroll
        for (int m = 0; m < 8; ++m) { float d = t8[m]-mu; q2 = fmaf(d,d,q2); }
        float rstd = rsqrtf(q2*0.125f + EPSF);
        #pragma unroll
        for (int m = 0; m < 8; ++m) t8[m] = (t8[m]-mu)*rstd*ci_ln_w[m] + ci_ln_b[m];
        f4v qa = gelu4((f4v){t8[0],t8[1],t8[2],t8[3]});
        f4v qb = gelu4((f4v){t8[4],t8[5],t8[6],t8[7]});
        t8[0]=qa[0]; t8[1]=qa[1]; t8[2]=qa[2]; t8[3]=qa[3];
        t8[4]=qb[0]; t8[5]=qb[1]; t8[6]=qb[2]; t8[7]=qb[3];
        if (t < 32) {
            float a = ci_b2[t];
            #pragma unroll
            for (int m = 0; m < 8; ++m) a = fmaf(wf[F_CI2T + m*32 + t], t8[m], a);
            segate_s[wid][t] = sigm(a);
        }
    }
    WSYNC();
    float sg[32];
    #pragma unroll
    for (int g = 0; g < 8; ++g) {
        f4v e = *(const f4v*)&segate_s[wid][g*4];
        #pragma unroll
        for (int r = 0; r < 4; ++r) {
            int o = g*4 + r;
            uint32 pkv = hidpk[16 + o/2];
            float gv = (o & 1) ? bh(pkv) : bl(pkv);
            sg[o] = gv * e[r];
        }
    }
    {   // SGU LayerNorm over 32
        float s = 0.f;
        #pragma unroll
        for (int o = 0; o < 32; ++o) s += sg[o];
        float mu = s * (1.f/32.f);
        float q2 = 0.f;
        #pragma unroll
        for (int o = 0; o < 32; ++o) { float d = sg[o]-mu; q2 = fmaf(d,d,q2); }
        float rstd = rsqrtf(q2*(1.f/32.f) + EPSF);
        #pragma unroll
        for (int o = 0; o < 32; ++o) sg[o] = (sg[o]-mu)*rstd*sgu_ln_w[o] + sgu_ln_b[o];
    }
    WSYNC();
    #pragma unroll
    for (int c8 = 0; c8 < 4; ++c8) {
        u4v w;
        #pragma unroll
        for (int j = 0; j < 4; ++j) w[j] = pk2(sg[c8*8+2*j], sg[c8*8+2*j+1]);
        *(u4v*)(Wp + t*72 + c8*8) = w;
    }
    WSYNC();

    // ---------------- P7: dwb_w0 GEMM -> write g1 TRANSPOSED (Gt, cols 32..63) ----------------
    bf8v dwb2W[2];
    {
        f4v accg[4][2];
        #pragma unroll
        for (int m = 0; m < 4; ++m) { accg[m][0] = (f4v){0.f,0.f,0.f,0.f}; accg[m][1] = (f4v){0.f,0.f,0.f,0.f}; }
        bf8v av[4];
        #pragma unroll
        for (int m = 0; m < 4; ++m) av[m] = *(const bf8v*)(Wp + (m*16 + l4)*72 + g4*8);
        #pragma unroll
        for (int m = 0; m < 4; ++m)
            #pragma unroll
            for (int n = 0; n < 2; ++n)
                accg[m][n] = __builtin_amdgcn_mfma_f32_16x16x32_bf16(av[m], dwb0W[n], accg[m][n], 0,0,0);
        // prefetch dwb_w2 weights (consumed in P9, after the long P8 phase)
        #pragma unroll
        for (int n = 0; n < 2; ++n)
            dwb2W[n] = *(const bf8v*)(wsw + W_DWB2_OFF + (n*16+l4)*32 + g4*8);
        WSYNC();
        #pragma unroll
        for (int m = 0; m < 4; ++m)
            #pragma unroll
            for (int n = 0; n < 2; ++n)
                #pragma unroll
                for (int r = 0; r < 4; ++r) {
                    int q = m*16 + g4*4 + r;
                    Wp[((q>>5)*32 + n*16 + l4)*72 + 32 + (q & 31)] = bfr(accg[m][n][r]);
                }
    }
    WSYNC();

    // ---------------- P8: idw kernel gen + dynamic 7x7 via MFMA (K-split M build) ----------------
    float t8b[8];
    #pragma unroll
    for (int m = 0; m < 8; ++m) t8b[m] = idw_b1[m];
    #pragma unroll 1
    for (int c = 0; c < 32; ++c) {      // g1 row t = Gt column t
        float gv = bl((uint32)Wp[((t>>5)*32 + c)*72 + 32 + (t & 31)]);
        #pragma unroll
        for (int m = 0; m < 8; ++m) t8b[m] = fmaf(wf[F_IW1T + c*8 + m], gv, t8b[m]);
    }
    #pragma unroll
    for (int m = 0; m < 8; ++m)
        t8b[m] = fmaxf(t8b[m]*(idw_bn_w[m]*0.9999950000374997f) + idw_bn_b[m], 0.f);

    f4v accd[4][2];
    #pragma unroll
    for (int m = 0; m < 4; ++m) { accd[m][0] = (f4v){0.f,0.f,0.f,0.f}; accd[m][1] = (f4v){0.f,0.f,0.f,0.f}; }
    #pragma unroll 1
    for (int s = 0; s < 2; ++s) {
        WSYNC();
        #pragma unroll
        for (int i = 0; i < 4; ++i) *(u4v*)(Wp + t*72 + i*8) = (u4v){0,0,0,0};
        #pragma unroll 1
        for (int ki = 0; ki < 7; ++ki) {
            int rr = py + ki - 3;
            #pragma unroll 1
            for (int kj = 0; kj < 7; ++kj) {
                int cc = px + kj - 3;
                int k  = ki*7 + kj;
                float wk = idw_b2[k];
                #pragma unroll
                for (int m = 0; m < 8; ++m) wk = fmaf(idw_w2[k*8 + m], t8b[m], wk);
                int q = rr*8 + cc;
                if (((unsigned)rr < 8u) && ((unsigned)cc < 8u) && ((q >> 5) == s))
                    Wp[t*72 + (q & 31)] = bfr(wk);
            }
        }
        WSYNC();
        bf8v aM[4], bG[2];
        #pragma unroll
        for (int m = 0; m < 4; ++m) aM[m] = *(const bf8v*)(Wp + (m*16 + l4)*72 + g4*8);
        #pragma unroll
        for (int n = 0; n < 2; ++n) bG[n] = *(const bf8v*)(Wp + (s*32 + n*16 + l4)*72 + 32 + g4*8);
        #pragma unroll
        for (int m = 0; m < 4; ++m)
            #pragma unroll
            for (int n = 0; n < 2; ++n)
                accd[m][n] = __builtin_amdgcn_mfma_f32_16x16x32_bf16(aM[m], bG[n], accd[m][n], 0,0,0);
    }
    WSYNC();
    #pragma unroll
    for (int m = 0; m < 4; ++m)
        #pragma unroll
        for (int n = 0; n < 2; ++n)
            #pragma unroll
            for (int r = 0; r < 4; ++r)
                Wp[(m*16 + g4*4 + r)*72 + n*16 + l4] = bfr(accd[m][n][r]);
    WSYNC();

    // ---------------- P9: dwb_w2 GEMM -> sgu = g2 * res ----------------
    bf8v outW[8];
    {
        f4v accg[4][2];
        #pragma unroll
        for (int m = 0; m < 4; ++m) { accg[m][0] = (f4v){0.f,0.f,0.f,0.f}; accg[m][1] = (f4v){0.f,0.f,0.f,0.f}; }
        bf8v av[4];
        #pragma unroll
        for (int m = 0; m < 4; ++m) av[m] = *(const bf8v*)(Wp + (m*16 + l4)*72 + g4*8);
        #pragma unroll
        for (int m = 0; m < 4; ++m)
            #pragma unroll
            for (int n = 0; n < 2; ++n)
                accg[m][n] = __builtin_amdgcn_mfma_f32_16x16x32_bf16(av[m], dwb2W[n], accg[m][n], 0,0,0);
        // prefetch out weights (consumed in P11, after the P10 phase)
        #pragma unroll
        for (int s = 0; s < 2; ++s)
            #pragma unroll
            for (int n = 0; n < 4; ++n)
                outW[s*4+n] = *(const bf8v*)(wsw + W_OUT_OFF + (n*16+l4)*64 + s*32 + g4*8);
        WSYNC();
        #pragma unroll
        for (int m = 0; m < 4; ++m)
            #pragma unroll
            for (int n = 0; n < 2; ++n)
                #pragma unroll
                for (int r = 0; r < 4; ++r)
                    Wp[(m*16 + g4*4 + r)*72 + n*16 + l4] = bfr(accg[m][n][r]);
        WSYNC();
    }
    float sgu[32];
    #pragma unroll
    for (int q8 = 0; q8 < 4; ++q8) {
        u4v v = *(const u4v*)(Wp + t*72 + q8*8);
        #pragma unroll
        for (int j = 0; j < 4; ++j) {
            int q = q8*4 + j;
            sgu[2*q]   = bl(v[j]) * bl(hidpk[q]);
            sgu[2*q+1] = bh(v[j]) * bh(hidpk[q]);
        }
    }
    WSYNC();

    // ---------------- P10: stage sgu (cols 32..63), si gate, stage xp*siv ----------------
    #pragma unroll
    for (int c8 = 0; c8 < 4; ++c8) {
        u4v w;
        #pragma unroll
        for (int j = 0; j < 4; ++j) w[j] = pk2(sgu[c8*8+2*j], sgu[c8*8+2*j+1]);
        *(u4v*)(Wp + t*72 + 32 + c8*8) = w;
    }
    WSYNC();
    float siv;
    {
        float s1[4];
        #pragma unroll
        for (int m = 0; m < 4; ++m) s1[m] = si_b1[m];
        #pragma unroll 1
        for (int c8 = 0; c8 < 4; ++c8) {
            u4v v = *(const u4v*)(Wp + t*72 + 32 + c8*8);
            #pragma unroll
            for (int j = 0; j < 4; ++j) {
                int c = c8*8 + 2*j;
                float a0 = bl(v[j]), a1 = bh(v[j]);
                #pragma unroll
                for (int m = 0; m < 4; ++m) {
                    s1[m] = fmaf(wf[F_SI1T + c*4 + m],     a0, s1[m]);
                    s1[m] = fmaf(wf[F_SI1T + (c+1)*4 + m], a1, s1[m]);
                }
            }
        }
        float s = s1[0]+s1[1]+s1[2]+s1[3];
        float mu = s * 0.25f;
        float q2 = 0.f;
        #pragma unroll
        for (int m = 0; m < 4; ++m) { float d = s1[m]-mu; q2 = fmaf(d,d,q2); }
        float rstd = rsqrtf(q2*0.25f + EPSF);
        f4v q;
        #pragma unroll
        for (int m = 0; m < 4; ++m) q[m] = (s1[m]-mu)*rstd*si_ln_w[m] + si_ln_b[m];
        q = gelu4(q);
        float a = si_b2[0];
        #pragma unroll
        for (int m = 0; m < 4; ++m) a = fmaf(si_w2[m], q[m], a);
        siv = sigm(a);
    }
    #pragma unroll
    for (int c8 = 0; c8 < 4; ++c8) {
        u4v w;
        #pragma unroll
        for (int j = 0; j < 4; ++j) {
            int q = c8*4 + j;
            w[j] = pk2(bl(xppk[q])*siv, bh(xppk[q])*siv);
        }
        *(u4v*)(Wp + t*72 + c8*8) = w;
    }
    WSYNC();

    // ---------------- P11: out GEMM + bias ----------------
    #pragma unroll
    for (int m = 0; m < 4; ++m)
        #pragma unroll
        for (int n = 0; n < 4; ++n)
            acc[m][n] = (f4v){0.f,0.f,0.f,0.f};
    {
        bf8v a0[4], a1[4];
        #pragma unroll
        for (int m = 0; m < 4; ++m) a0[m] = *(const bf8v*)(Wp + (m*16 + l4)*72 + g4*8);
        #pragma unroll
        for (int m = 0; m < 4; ++m) a1[m] = *(const bf8v*)(Wp + (m*16 + l4)*72 + 32 + g4*8);
        #pragma unroll
        for (int m = 0; m < 4; ++m)
            #pragma unroll
            for (int n = 0; n < 4; ++n)
                acc[m][n] = __builtin_amdgcn_mfma_f32_16x16x32_bf16(a0[m], outW[n], acc[m][n], 0,0,0);
        #pragma unroll
        for (int m = 0; m < 4; ++m)
            #pragma unroll
            for (int n = 0; n < 4; ++n)
                acc[m][n] = __builtin_amdgcn_mfma_f32_16x16x32_bf16(a1[m], outW[4+n], acc[m][n], 0,0,0);
    }
    {
        float bo[4];
        #pragma unroll
        for (int n = 0; n < 4; ++n) bo[n] = out_b[n*16 + l4];
        #pragma unroll
        for (int m = 0; m < 4; ++m)
            #pragma unroll
            for (int n = 0; n < 4; ++n)
                #pragma unroll
                for (int r = 0; r < 4; ++r)
                    acc[m][n][r] += bo[n];
    }
    WSYNC();
    #pragma unroll
    for (int m = 0; m < 4; ++m)
        #pragma unroll
        for (int n = 0; n < 4; ++n)
            #pragma unroll
            for (int r = 0; r < 4; ++r)
                Wp[(m*16 + g4*4 + r)*72 + n*16 + l4] = bfr(acc[m][n][r]);
    __syncthreads();

    // ---------------- P12: cooperative coalesced store (nontemporal) ----------------
    {
        float* obase = out + (bb*64)*HWSZ + (ph*8)*256 + strip*32;
        const unsigned short* lsrc = bufS + lp*PSTR + (ty*8 + lpx)*72;
        #pragma unroll 1
        for (int c8 = 0; c8 < 8; ++c8) {
            u4v v = *(const u4v*)(lsrc + c8*8);
            #pragma unroll
            for (int j = 0; j < 4; ++j) {
                int c = c8*8 + 2*j;
                __builtin_nontemporal_store(bl(v[j]), obase + c*HWSZ + yx);
                __builtin_nontemporal_store(bh(v[j]), obase + (c+1)*HWSZ + yx);
            }
        }
    }
}

extern "C" void kernel_launch(void* const* d_in, const int* in_sizes, int n_in,
                              void* d_out, int out_size, void* d_ws, size_t ws_size,
                              hipStream_t stream) {
    const float* p[35];
    for (int i = 0; i < 35; ++i) p[i] = (const float*)d_in[i];
    unsigned short* ws = (unsigned short*)d_ws;
    float* wsf = (float*)ws + 8192;

    prep_w<<<64, 256, 0, stream>>>(p[1], p[3], p[21], p[23], p[27], p[34], ws);
    prep_t<<<7, 256, 0, stream>>>(p[7], p[9], p[13], p[28], p[15], wsf);

    const int B = in_sizes[0] / (64 * 256 * 256);   // = 4
    dim3 grid(B * 32 * 8), block(256);
    gmlp_fused<<<grid, block, 0, stream>>>(
        p[0],  p[2],  p[4],  p[5],  p[6],  p[8],
        p[10], p[11], p[12], p[14],
        p[16], p[17], p[18], p[19], p[20],
        p[22], p[24], p[25], p[26],
        p[29], p[30], p[31], p[32], p[33],
        ws, (float*)d_out);
}